// Round 1
// baseline (201.764 us; speedup 1.0000x reference)
//
#include <hip/hip_runtime.h>

#define E_DIM 1024
#define NHEAD 16
#define HDIM 64
#define SEQ 2048
#define NBATCH 2
#define WIN 256
#define MTOK (NBATCH * SEQ) // 4096

typedef __attribute__((ext_vector_type(4))) float f32x4;
typedef __attribute__((ext_vector_type(8))) short short8;
typedef __attribute__((ext_vector_type(4))) unsigned short u16x4;

#define AS1 __attribute__((address_space(1)))
#define AS3 __attribute__((address_space(3)))

__device__ __forceinline__ void gll16(const void* g, void* l) {
    __builtin_amdgcn_global_load_lds((const AS1 void*)g, (AS3 void*)l, 16, 0, 0);
}

__device__ __forceinline__ unsigned short f2bf(float f) {
    union { float f; unsigned u; } a; a.f = f;
    unsigned r = a.u + 0x7fffu + ((a.u >> 16) & 1u);
    return (unsigned short)(r >> 16);
}

// ---------------- fp32 -> bf16 conversion ----------------
__global__ __launch_bounds__(256) void conv_f2b(const float* __restrict__ src,
                                                unsigned short* __restrict__ dst, int n4) {
    int i = blockIdx.x * 256 + threadIdx.x;
    int stride = gridDim.x * 256;
    for (; i < n4; i += stride) {
        float4 v = ((const float4*)src)[i];
        u16x4 o;
        o[0] = f2bf(v.x); o[1] = f2bf(v.y); o[2] = f2bf(v.z); o[3] = f2bf(v.w);
        ((u16x4*)dst)[i] = o;
    }
}

// ---------------- shared GEMM mainloop ----------------
// C(128x128) = A[m0:,:] (MxK bf16, K=1024 row-major) @ Bw[n0:,:]^T (N x K bf16 row-major)
// BK=64, 4 waves (2x2 of 64x64), LDS XOR-swizzle on 16B slots: phys_slot = slot ^ (row&7)
__device__ __forceinline__ void gemm_tile(const unsigned short* __restrict__ A,
                                          const unsigned short* __restrict__ Bw,
                                          int m0, int n0,
                                          f32x4 acc[4][4], char* ldsA, char* ldsB) {
    const int t = threadIdx.x;
    const int w = t >> 6, l = t & 63;
    const int r16 = l & 15, kq = l >> 4;
    const int wr = w >> 1, wc = w & 1;
    const int srow = l >> 3, ps = l & 7;

    for (int kt = 0; kt < E_DIM / 64; ++kt) {
        // stage A-tile (128x64 bf16 = 16KB) and B-tile via global_load_lds width 16
        #pragma unroll
        for (int c = 0; c < 4; ++c) {
            int chunk = w * 4 + c;           // 0..15, wave-uniform
            int row = chunk * 8 + srow;      // 0..127
            int kslot = ps ^ (row & 7);      // inverse-swizzled source
            gll16(A  + (size_t)(m0 + row) * E_DIM + kt * 64 + kslot * 8, ldsA + chunk * 1024);
            gll16(Bw + (size_t)(n0 + row) * E_DIM + kt * 64 + kslot * 8, ldsB + chunk * 1024);
        }
        __syncthreads();
        #pragma unroll
        for (int kk = 0; kk < 2; ++kk) {
            short8 af[4], bfr[4];
            #pragma unroll
            for (int m = 0; m < 4; ++m) {
                int rr = wr * 64 + m * 16 + r16;
                int c = kk * 4 + kq;
                af[m] = *(const short8*)(ldsA + rr * 128 + ((c ^ (rr & 7)) * 16));
            }
            #pragma unroll
            for (int n = 0; n < 4; ++n) {
                int rr = wc * 64 + n * 16 + r16;
                int c = kk * 4 + kq;
                bfr[n] = *(const short8*)(ldsB + rr * 128 + ((c ^ (rr & 7)) * 16));
            }
            #pragma unroll
            for (int m = 0; m < 4; ++m)
                #pragma unroll
                for (int n = 0; n < 4; ++n)
                    acc[m][n] = __builtin_amdgcn_mfma_f32_16x16x32_bf16(af[m], bfr[n], acc[m][n], 0, 0, 0);
        }
        __syncthreads();
    }
}

// ---------------- QKV projection ----------------
__global__ __launch_bounds__(256) void gemm_qkv(const unsigned short* __restrict__ xb,
        const unsigned short* __restrict__ wqb, const unsigned short* __restrict__ wkb,
        const unsigned short* __restrict__ wvb,
        const float* __restrict__ bq, const float* __restrict__ bk, const float* __restrict__ bv,
        unsigned short* __restrict__ qo, unsigned short* __restrict__ ko, unsigned short* __restrict__ vo) {
    __shared__ char lds[32768];
    const int m0 = blockIdx.x * 128;
    const int by = blockIdx.y;
    const int mat = by >> 3;
    const int nb0 = (by & 7) * 128;
    const unsigned short* Bw = (mat == 0) ? wqb : (mat == 1) ? wkb : wvb;
    const float* bias = (mat == 0) ? bq : (mat == 1) ? bk : bv;
    unsigned short* dst = (mat == 0) ? qo : (mat == 1) ? ko : vo;
    const float scale = (mat == 0) ? 0.125f : 1.0f;  // D^-0.5 folded into Q

    f32x4 acc[4][4];
    #pragma unroll
    for (int m = 0; m < 4; ++m)
        #pragma unroll
        for (int n = 0; n < 4; ++n)
            acc[m][n] = (f32x4){0.f, 0.f, 0.f, 0.f};

    gemm_tile(xb, Bw, m0, nb0, acc, lds, lds + 16384);

    const int t = threadIdx.x;
    const int w = t >> 6, l = t & 63;
    const int r16 = l & 15, kq = l >> 4;
    const int wr = w >> 1, wc = w & 1;
    #pragma unroll
    for (int n = 0; n < 4; ++n) {
        int e = nb0 + wc * 64 + n * 16 + r16;
        float bb = bias[e];
        int h = e >> 6, d = e & 63;
        #pragma unroll
        for (int m = 0; m < 4; ++m) {
            #pragma unroll
            for (int r = 0; r < 4; ++r) {
                int tok = m0 + wr * 64 + m * 16 + kq * 4 + r;
                int b = tok >> 11, s = tok & (SEQ - 1);
                float val = (acc[m][n][r] + bb) * scale;
                dst[((size_t)(b * NHEAD + h) * SEQ + s) * HDIM + d] = f2bf(val);
            }
        }
    }
}

// ---------------- V transpose: (bh, s, d) -> (bh, d, s) ----------------
__global__ __launch_bounds__(256) void transpose_v(const unsigned short* __restrict__ v,
                                                   unsigned short* __restrict__ vT) {
    __shared__ unsigned short tile[64][72];
    const int bh = blockIdx.x >> 5;
    const int s0 = (blockIdx.x & 31) * 64;
    const int t = threadIdx.x;
    const int rr = t >> 3;        // 0..31
    const int c8 = (t & 7) * 8;   // 0..56
    #pragma unroll
    for (int i = 0; i < 2; ++i) {
        int s = i * 32 + rr;
        short8 vv = *(const short8*)(v + ((size_t)bh * SEQ + s0 + s) * HDIM + c8);
        #pragma unroll
        for (int j = 0; j < 8; ++j) tile[s][c8 + j] = (unsigned short)vv[j];
    }
    __syncthreads();
    #pragma unroll
    for (int i = 0; i < 2; ++i) {
        int d = i * 32 + rr;
        short8 ov;
        #pragma unroll
        for (int j = 0; j < 8; ++j) ov[j] = (short)tile[c8 + j][d];
        *(short8*)(vT + ((size_t)bh * HDIM + d) * SEQ + s0 + c8) = ov;
    }
}

// ---------------- sliding-window flash attention ----------------
// 1 wave per 16 query rows; KBLK=32; Q pre-scaled; K rows / V^T rows read direct
// from global (L2-resident); P relayout C-frag->A-frag via per-wave swizzled LDS.
__global__ __launch_bounds__(256) void attn_swa(const unsigned short* __restrict__ q,
                                                const unsigned short* __restrict__ k,
                                                const unsigned short* __restrict__ vT,
                                                unsigned short* __restrict__ y) {
    __shared__ char plds[4 * 2048];  // per-wave [16 rows][64 cols] bf16, slot-swizzled
    const int t = threadIdx.x;
    const int w = t >> 6, l = t & 63;
    const int r16 = l & 15, kq = l >> 4;
    const int wid = blockIdx.x * 4 + w;
    const int bh = wid >> 7;             // 0..31
    const int q0 = (wid & 127) * 16;
    const unsigned short* qp = q + (size_t)bh * SEQ * HDIM;
    const unsigned short* kp = k + (size_t)bh * SEQ * HDIM;
    const unsigned short* vp = vT + (size_t)bh * HDIM * SEQ;
    char* pl = plds + w * 2048;

    short8 qf0 = *(const short8*)(qp + (q0 + r16) * HDIM + kq * 8);
    short8 qf1 = *(const short8*)(qp + (q0 + r16) * HDIM + 32 + kq * 8);

    f32x4 po[4];
    #pragma unroll
    for (int nn = 0; nn < 4; ++nn) po[nn] = (f32x4){0.f, 0.f, 0.f, 0.f};
    float mrow[4] = {-1e30f, -1e30f, -1e30f, -1e30f};
    float lrow[4] = {0.f, 0.f, 0.f, 0.f};

    const int kstart = (q0 >= WIN) ? ((q0 - WIN) & ~31) : 0;
    for (int k0 = kstart; k0 <= q0 + 15; k0 += 32) {
        f32x4 sc[2];
        #pragma unroll
        for (int n = 0; n < 2; ++n) {
            const unsigned short* kr = kp + (size_t)(k0 + n * 16 + r16) * HDIM + kq * 8;
            short8 kf0 = *(const short8*)(kr);
            short8 kf1 = *(const short8*)(kr + 32);
            f32x4 z = {0.f, 0.f, 0.f, 0.f};
            z = __builtin_amdgcn_mfma_f32_16x16x32_bf16(qf0, kf0, z, 0, 0, 0);
            sc[n] = __builtin_amdgcn_mfma_f32_16x16x32_bf16(qf1, kf1, z, 0, 0, 0);
        }
        // mask + row max (C-frag: row=(lane>>4)*4+reg, col=lane&15)
        float tmax[4];
        #pragma unroll
        for (int r = 0; r < 4; ++r) {
            int qrow = q0 + kq * 4 + r;
            int key0 = k0 + r16;
            int key1 = key0 + 16;
            if (!(key0 <= qrow && key0 >= qrow - WIN)) sc[0][r] = -1e30f;
            if (!(key1 <= qrow && key1 >= qrow - WIN)) sc[1][r] = -1e30f;
            tmax[r] = fmaxf(sc[0][r], sc[1][r]);
        }
        #pragma unroll
        for (int off = 1; off < 16; off <<= 1) {
            #pragma unroll
            for (int r = 0; r < 4; ++r)
                tmax[r] = fmaxf(tmax[r], __shfl_xor(tmax[r], off));
        }
        float pv0[4], pv1[4], psum[4];
        #pragma unroll
        for (int r = 0; r < 4; ++r) {
            float mnew = fmaxf(mrow[r], tmax[r]);
            float resc = __expf(mrow[r] - mnew);
            mrow[r] = mnew;
            lrow[r] *= resc;
            po[0][r] *= resc; po[1][r] *= resc; po[2][r] *= resc; po[3][r] *= resc;
            float p0 = (sc[0][r] > -1e29f) ? __expf(sc[0][r] - mnew) : 0.f;
            float p1 = (sc[1][r] > -1e29f) ? __expf(sc[1][r] - mnew) : 0.f;
            pv0[r] = p0; pv1[r] = p1;
            psum[r] = p0 + p1;
        }
        #pragma unroll
        for (int off = 1; off < 16; off <<= 1) {
            #pragma unroll
            for (int r = 0; r < 4; ++r)
                psum[r] += __shfl_xor(psum[r], off);
        }
        #pragma unroll
        for (int r = 0; r < 4; ++r) lrow[r] += psum[r];

        // P (C-layout) -> LDS with 16B-slot XOR swizzle -> A-frag
        #pragma unroll
        for (int r = 0; r < 4; ++r) {
            int row = kq * 4 + r;
            int c0 = r16 ^ ((row & 7) << 3);
            int c1 = (16 + r16) ^ ((row & 7) << 3);
            *(unsigned short*)(pl + row * 128 + c0 * 2) = f2bf(pv0[r]);
            *(unsigned short*)(pl + row * 128 + c1 * 2) = f2bf(pv1[r]);
        }
        short8 pa = *(const short8*)(pl + r16 * 128 + ((kq ^ (r16 & 7)) * 16));
        #pragma unroll
        for (int nn = 0; nn < 4; ++nn) {
            short8 vf = *(const short8*)(vp + (size_t)(nn * 16 + r16) * SEQ + k0 + kq * 8);
            po[nn] = __builtin_amdgcn_mfma_f32_16x16x32_bf16(pa, vf, po[nn], 0, 0, 0);
        }
    }

    const int b = bh >> 4, h = bh & 15;
    #pragma unroll
    for (int nn = 0; nn < 4; ++nn) {
        #pragma unroll
        for (int r = 0; r < 4; ++r) {
            int s = q0 + kq * 4 + r;
            float val = po[nn][r] / lrow[r];
            y[((size_t)(b * SEQ + s)) * E_DIM + h * HDIM + nn * 16 + r16] = f2bf(val);
        }
    }
}

// ---------------- output projection (fp32 out) ----------------
__global__ __launch_bounds__(256) void gemm_out(const unsigned short* __restrict__ yb,
        const unsigned short* __restrict__ wob, const float* __restrict__ bo,
        float* __restrict__ out) {
    __shared__ char lds[32768];
    const int m0 = blockIdx.x * 128;
    const int n0 = blockIdx.y * 128;
    f32x4 acc[4][4];
    #pragma unroll
    for (int m = 0; m < 4; ++m)
        #pragma unroll
        for (int n = 0; n < 4; ++n)
            acc[m][n] = (f32x4){0.f, 0.f, 0.f, 0.f};

    gemm_tile(yb, wob, m0, n0, acc, lds, lds + 16384);

    const int t = threadIdx.x;
    const int w = t >> 6, l = t & 63;
    const int r16 = l & 15, kq = l >> 4;
    const int wr = w >> 1, wc = w & 1;
    #pragma unroll
    for (int n = 0; n < 4; ++n) {
        int e = n0 + wc * 64 + n * 16 + r16;
        float bb = bo[e];
        #pragma unroll
        for (int m = 0; m < 4; ++m) {
            #pragma unroll
            for (int r = 0; r < 4; ++r) {
                int tok = m0 + wr * 64 + m * 16 + kq * 4 + r;
                out[(size_t)tok * E_DIM + e] = acc[m][n][r] + bb;
            }
        }
    }
}

extern "C" void kernel_launch(void* const* d_in, const int* in_sizes, int n_in,
                              void* d_out, int out_size, void* d_ws, size_t ws_size,
                              hipStream_t stream) {
    const float* x  = (const float*)d_in[0];
    const float* Wq = (const float*)d_in[1];
    const float* Wk = (const float*)d_in[2];
    const float* Wv = (const float*)d_in[3];
    const float* Wo = (const float*)d_in[4];
    const float* bq = (const float*)d_in[5];
    const float* bk = (const float*)d_in[6];
    const float* bv = (const float*)d_in[7];
    const float* bo = (const float*)d_in[8];
    float* out = (float*)d_out;

    char* ws = (char*)d_ws;
    unsigned short* xb  = (unsigned short*)(ws);                        // 8 MB
    unsigned short* wqb = (unsigned short*)(ws + ((size_t)8 << 20));    // 2 MB
    unsigned short* wkb = (unsigned short*)(ws + ((size_t)10 << 20));   // 2 MB
    unsigned short* wvb = (unsigned short*)(ws + ((size_t)12 << 20));   // 2 MB
    unsigned short* wob = (unsigned short*)(ws + ((size_t)14 << 20));   // 2 MB
    unsigned short* qw  = (unsigned short*)(ws + ((size_t)16 << 20));   // 8 MB
    unsigned short* kw  = (unsigned short*)(ws + ((size_t)24 << 20));   // 8 MB
    unsigned short* vw  = (unsigned short*)(ws + ((size_t)32 << 20));   // 8 MB
    unsigned short* vTw = (unsigned short*)(ws + ((size_t)40 << 20));   // 8 MB
    unsigned short* yw  = (unsigned short*)(ws + ((size_t)48 << 20));   // 8 MB

    conv_f2b<<<4096, 256, 0, stream>>>(x, xb, MTOK * E_DIM / 4);
    conv_f2b<<<1024, 256, 0, stream>>>(Wq, wqb, E_DIM * E_DIM / 4);
    conv_f2b<<<1024, 256, 0, stream>>>(Wk, wkb, E_DIM * E_DIM / 4);
    conv_f2b<<<1024, 256, 0, stream>>>(Wv, wvb, E_DIM * E_DIM / 4);
    conv_f2b<<<1024, 256, 0, stream>>>(Wo, wob, E_DIM * E_DIM / 4);

    gemm_qkv<<<dim3(32, 24), 256, 0, stream>>>(xb, wqb, wkb, wvb, bq, bk, bv, qw, kw, vw);
    transpose_v<<<1024, 256, 0, stream>>>(vw, vTw);
    attn_swa<<<1024, 256, 0, stream>>>(qw, kw, vTw, yw);
    gemm_out<<<dim3(32, 8), 256, 0, stream>>>(yw, wob, bo, out);
}

// Round 2
// 188.019 us; speedup vs baseline: 1.0731x; 1.0731x over previous
//
#include <hip/hip_runtime.h>

#define E_DIM 1024
#define NHEAD 16
#define HDIM 64
#define SEQ 2048
#define NBATCH 2
#define WIN 256
#define MTOK (NBATCH * SEQ) // 4096
#define BKT 32              // K per pipeline tile in gemm8
#define NT (E_DIM / BKT)    // 32 tiles

typedef __attribute__((ext_vector_type(4))) float f32x4;
typedef __attribute__((ext_vector_type(8))) short short8;
typedef __attribute__((ext_vector_type(4))) unsigned short u16x4;

#define AS1 __attribute__((address_space(1)))
#define AS3 __attribute__((address_space(3)))

__device__ __forceinline__ void gll16(const void* g, void* l) {
    __builtin_amdgcn_global_load_lds((const AS1 void*)g, (AS3 void*)l, 16, 0, 0);
}

__device__ __forceinline__ unsigned short f2bf(float f) {
    union { float f; unsigned u; } a; a.f = f;
    unsigned r = a.u + 0x7fffu + ((a.u >> 16) & 1u);
    return (unsigned short)(r >> 16);
}

// ---------------- fp32 -> bf16 conversion (x) ----------------
__global__ __launch_bounds__(256) void conv_f2b(const float* __restrict__ src,
                                                unsigned short* __restrict__ dst, int n4) {
    int i = blockIdx.x * 256 + threadIdx.x;
    int stride = gridDim.x * 256;
    for (; i < n4; i += stride) {
        float4 v = ((const float4*)src)[i];
        u16x4 o;
        o[0] = f2bf(v.x); o[1] = f2bf(v.y); o[2] = f2bf(v.z); o[3] = f2bf(v.w);
        ((u16x4*)dst)[i] = o;
    }
}

// ---------------- fp32 -> bf16 for the 4 weight matrices, one launch ----------------
__global__ __launch_bounds__(256) void conv_w4(const float* __restrict__ w0, const float* __restrict__ w1,
                                               const float* __restrict__ w2, const float* __restrict__ w3,
                                               unsigned short* __restrict__ o0, unsigned short* __restrict__ o1,
                                               unsigned short* __restrict__ o2, unsigned short* __restrict__ o3) {
    const int m = blockIdx.y;
    const float* src = (m == 0) ? w0 : (m == 1) ? w1 : (m == 2) ? w2 : w3;
    unsigned short* dst = (m == 0) ? o0 : (m == 1) ? o1 : (m == 2) ? o2 : o3;
    int i = blockIdx.x * 256 + threadIdx.x;   // grid.x = 1024 -> covers 262144 float4 chunks
    float4 v = ((const float4*)src)[i];
    u16x4 o;
    o[0] = f2bf(v.x); o[1] = f2bf(v.y); o[2] = f2bf(v.z); o[3] = f2bf(v.w);
    ((u16x4*)dst)[i] = o;
}

// ---------------- 8-phase-style QKV GEMM ----------------
// C(256x256) = A[m0:,:] (4096x1024 bf16 row-major) @ Bw[nb:,:]^T (1024x1024 bf16 row-major)
// 512 threads = 8 waves (2M x 4N), per-wave C = 128x64 (acc[8][4]).
// Pipeline: 4 LDS slots x (A 16KB + B 16KB), 1 unit staged per phase,
// counted vmcnt(4) at tile boundaries only, raw s_barrier, setprio around MFMA.
__global__ __launch_bounds__(512, 2) void gemm8_qkv(const unsigned short* __restrict__ xb,
        const unsigned short* __restrict__ wqb, const unsigned short* __restrict__ wkb,
        const unsigned short* __restrict__ wvb,
        const float* __restrict__ bq, const float* __restrict__ bk, const float* __restrict__ bv,
        unsigned short* __restrict__ qo, unsigned short* __restrict__ ko,
        unsigned short* __restrict__ vTo) {
    __shared__ char lds[131072];
    const int tid = threadIdx.x;
    const int w = tid >> 6, l = tid & 63;
    const int r16 = l & 15, kq = l >> 4;
    const int wm = w >> 2, wn = w & 3;
    const int m0 = blockIdx.x * 256;
    const int by = blockIdx.y;            // 0..11
    const int mat = by >> 2;              // 0:Q 1:K 2:V
    const int nb = (by & 3) * 256;        // col offset inside the matrix
    const unsigned short* Bw = (mat == 0) ? wqb : (mat == 1) ? wkb : wvb;

    // staging geometry: unit = one 256x32 k-panel (16KB); chunk = i*512 + tid
    const int srow = tid >> 2;            // 0..127
    const int sslot = tid & 3;            // 16B slot within 64B row
    const unsigned short* aSrc0 = xb + (size_t)(m0 + srow) * E_DIM + sslot * 8;
    const unsigned short* aSrc1 = aSrc0 + (size_t)128 * E_DIM;
    const unsigned short* bSrc0 = Bw + (size_t)(nb + srow) * E_DIM + sslot * 8;
    const unsigned short* bSrc1 = bSrc0 + (size_t)128 * E_DIM;
    const int dstOff = w * 1024;          // wave-uniform chunk base (bytes)

#define STAGE_A(t) { char* d_ = lds + ((t) & 3) * 32768 + dstOff; \
                     gll16(aSrc0 + (t) * BKT, d_); gll16(aSrc1 + (t) * BKT, d_ + 8192); }
#define STAGE_B(t) { char* d_ = lds + ((t) & 3) * 32768 + 16384 + dstOff; \
                     gll16(bSrc0 + (t) * BKT, d_); gll16(bSrc1 + (t) * BKT, d_ + 8192); }

    f32x4 acc[8][4];
    #pragma unroll
    for (int m = 0; m < 8; ++m)
        #pragma unroll
        for (int n = 0; n < 4; ++n)
            acc[m][n] = (f32x4){0.f, 0.f, 0.f, 0.f};

    // prologue: tiles 0 and 1 in flight (8 loads/thread)
    STAGE_A(0); STAGE_B(0); STAGE_A(1); STAGE_B(1);

    for (int t = 0; t < NT; ++t) {
        if (t < NT - 1) { asm volatile("s_waitcnt vmcnt(4)" ::: "memory"); }
        else            { asm volatile("s_waitcnt vmcnt(0)" ::: "memory"); }
        __builtin_amdgcn_sched_barrier(0);
        __builtin_amdgcn_s_barrier();
        __builtin_amdgcn_sched_barrier(0);
        char* la = lds + (t & 3) * 32768;
        char* lb = la + 16384;
        // ---- phase 0: b[0..3], a(mh=0), stage A(t+2), 16 MFMA ----
        short8 bfr[4], af[4];
        #pragma unroll
        for (int n = 0; n < 4; ++n)
            bfr[n] = *(const short8*)(lb + (wn * 64 + n * 16 + r16) * 64 + kq * 16);
        #pragma unroll
        for (int j = 0; j < 4; ++j)
            af[j] = *(const short8*)(la + (wm * 128 + j * 16 + r16) * 64 + kq * 16);
        if (t + 2 < NT) STAGE_A(t + 2);
        __builtin_amdgcn_s_barrier();
        __builtin_amdgcn_sched_barrier(0);
        __builtin_amdgcn_s_setprio(1);
        #pragma unroll
        for (int j = 0; j < 4; ++j)
            #pragma unroll
            for (int n = 0; n < 4; ++n)
                acc[j][n] = __builtin_amdgcn_mfma_f32_16x16x32_bf16(af[j], bfr[n], acc[j][n], 0, 0, 0);
        __builtin_amdgcn_s_setprio(0);
        // ---- phase 1: a(mh=1), stage B(t+2), 16 MFMA ----
        short8 af2[4];
        #pragma unroll
        for (int j = 0; j < 4; ++j)
            af2[j] = *(const short8*)(la + (wm * 128 + (4 + j) * 16 + r16) * 64 + kq * 16);
        if (t + 2 < NT) STAGE_B(t + 2);
        __builtin_amdgcn_s_barrier();
        __builtin_amdgcn_sched_barrier(0);
        __builtin_amdgcn_s_setprio(1);
        #pragma unroll
        for (int j = 0; j < 4; ++j)
            #pragma unroll
            for (int n = 0; n < 4; ++n)
                acc[4 + j][n] = __builtin_amdgcn_mfma_f32_16x16x32_bf16(af2[j], bfr[n], acc[4 + j][n], 0, 0, 0);
        __builtin_amdgcn_s_setprio(0);
    }
#undef STAGE_A
#undef STAGE_B

    // epilogue
    const float* bias = (mat == 0) ? bq : (mat == 1) ? bk : bv;
    const float scale = (mat == 0) ? 0.125f : 1.0f;   // D^-0.5 folded into Q
    #pragma unroll
    for (int n = 0; n < 4; ++n) {
        int e = nb + wn * 64 + n * 16 + r16;          // col within this matrix [0,1024)
        float bb = bias[e];
        int h = e >> 6, d = e & 63;
        #pragma unroll
        for (int m = 0; m < 8; ++m) {
            int tok = m0 + wm * 128 + m * 16 + kq * 4;
            int b = tok >> 11, s = tok & (SEQ - 1);
            if (mat == 2) {
                // V written directly transposed: vT[(bh*64+d)*2048 + s], 4 consecutive s
                u16x4 o;
                #pragma unroll
                for (int r = 0; r < 4; ++r) o[r] = f2bf(acc[m][n][r] + bb);
                *(u16x4*)(vTo + ((size_t)(b * NHEAD + h) * HDIM + d) * SEQ + s) = o;
            } else {
                unsigned short* dst = (mat == 0) ? qo : ko;
                #pragma unroll
                for (int r = 0; r < 4; ++r) {
                    float val = (acc[m][n][r] + bb) * scale;
                    dst[((size_t)(b * NHEAD + h) * SEQ + s + r) * HDIM + d] = f2bf(val);
                }
            }
        }
    }
}

// ---------------- shared GEMM mainloop (128x128, used by gemm_out) ----------------
__device__ __forceinline__ void gemm_tile(const unsigned short* __restrict__ A,
                                          const unsigned short* __restrict__ Bw,
                                          int m0, int n0,
                                          f32x4 acc[4][4], char* ldsA, char* ldsB) {
    const int t = threadIdx.x;
    const int w = t >> 6, l = t & 63;
    const int r16 = l & 15, kq = l >> 4;
    const int wr = w >> 1, wc = w & 1;
    const int srow = l >> 3, ps = l & 7;

    for (int kt = 0; kt < E_DIM / 64; ++kt) {
        #pragma unroll
        for (int c = 0; c < 4; ++c) {
            int chunk = w * 4 + c;
            int row = chunk * 8 + srow;
            int kslot = ps ^ (row & 7);
            gll16(A  + (size_t)(m0 + row) * E_DIM + kt * 64 + kslot * 8, ldsA + chunk * 1024);
            gll16(Bw + (size_t)(n0 + row) * E_DIM + kt * 64 + kslot * 8, ldsB + chunk * 1024);
        }
        __syncthreads();
        #pragma unroll
        for (int kk = 0; kk < 2; ++kk) {
            short8 af[4], bfr[4];
            #pragma unroll
            for (int m = 0; m < 4; ++m) {
                int rr = wr * 64 + m * 16 + r16;
                int c = kk * 4 + kq;
                af[m] = *(const short8*)(ldsA + rr * 128 + ((c ^ (rr & 7)) * 16));
            }
            #pragma unroll
            for (int n = 0; n < 4; ++n) {
                int rr = wc * 64 + n * 16 + r16;
                int c = kk * 4 + kq;
                bfr[n] = *(const short8*)(ldsB + rr * 128 + ((c ^ (rr & 7)) * 16));
            }
            #pragma unroll
            for (int m = 0; m < 4; ++m)
                #pragma unroll
                for (int n = 0; n < 4; ++n)
                    acc[m][n] = __builtin_amdgcn_mfma_f32_16x16x32_bf16(af[m], bfr[n], acc[m][n], 0, 0, 0);
        }
        __syncthreads();
    }
}

// ---------------- sliding-window flash attention ----------------
__global__ __launch_bounds__(256) void attn_swa(const unsigned short* __restrict__ q,
                                                const unsigned short* __restrict__ k,
                                                const unsigned short* __restrict__ vT,
                                                unsigned short* __restrict__ y) {
    __shared__ char plds[4 * 2048];
    const int t = threadIdx.x;
    const int w = t >> 6, l = t & 63;
    const int r16 = l & 15, kq = l >> 4;
    const int wid = blockIdx.x * 4 + w;
    const int bh = wid >> 7;
    const int q0 = (wid & 127) * 16;
    const unsigned short* qp = q + (size_t)bh * SEQ * HDIM;
    const unsigned short* kp = k + (size_t)bh * SEQ * HDIM;
    const unsigned short* vp = vT + (size_t)bh * HDIM * SEQ;
    char* pl = plds + w * 2048;

    short8 qf0 = *(const short8*)(qp + (q0 + r16) * HDIM + kq * 8);
    short8 qf1 = *(const short8*)(qp + (q0 + r16) * HDIM + 32 + kq * 8);

    f32x4 po[4];
    #pragma unroll
    for (int nn = 0; nn < 4; ++nn) po[nn] = (f32x4){0.f, 0.f, 0.f, 0.f};
    float mrow[4] = {-1e30f, -1e30f, -1e30f, -1e30f};
    float lrow[4] = {0.f, 0.f, 0.f, 0.f};

    const int kstart = (q0 >= WIN) ? ((q0 - WIN) & ~31) : 0;
    for (int k0 = kstart; k0 <= q0 + 15; k0 += 32) {
        f32x4 sc[2];
        #pragma unroll
        for (int n = 0; n < 2; ++n) {
            const unsigned short* kr = kp + (size_t)(k0 + n * 16 + r16) * HDIM + kq * 8;
            short8 kf0 = *(const short8*)(kr);
            short8 kf1 = *(const short8*)(kr + 32);
            f32x4 z = {0.f, 0.f, 0.f, 0.f};
            z = __builtin_amdgcn_mfma_f32_16x16x32_bf16(qf0, kf0, z, 0, 0, 0);
            sc[n] = __builtin_amdgcn_mfma_f32_16x16x32_bf16(qf1, kf1, z, 0, 0, 0);
        }
        float tmax[4];
        #pragma unroll
        for (int r = 0; r < 4; ++r) {
            int qrow = q0 + kq * 4 + r;
            int key0 = k0 + r16;
            int key1 = key0 + 16;
            if (!(key0 <= qrow && key0 >= qrow - WIN)) sc[0][r] = -1e30f;
            if (!(key1 <= qrow && key1 >= qrow - WIN)) sc[1][r] = -1e30f;
            tmax[r] = fmaxf(sc[0][r], sc[1][r]);
        }
        #pragma unroll
        for (int off = 1; off < 16; off <<= 1) {
            #pragma unroll
            for (int r = 0; r < 4; ++r)
                tmax[r] = fmaxf(tmax[r], __shfl_xor(tmax[r], off));
        }
        float pv0[4], pv1[4], psum[4];
        #pragma unroll
        for (int r = 0; r < 4; ++r) {
            float mnew = fmaxf(mrow[r], tmax[r]);
            float resc = __expf(mrow[r] - mnew);
            mrow[r] = mnew;
            lrow[r] *= resc;
            po[0][r] *= resc; po[1][r] *= resc; po[2][r] *= resc; po[3][r] *= resc;
            float p0 = (sc[0][r] > -1e29f) ? __expf(sc[0][r] - mnew) : 0.f;
            float p1 = (sc[1][r] > -1e29f) ? __expf(sc[1][r] - mnew) : 0.f;
            pv0[r] = p0; pv1[r] = p1;
            psum[r] = p0 + p1;
        }
        #pragma unroll
        for (int off = 1; off < 16; off <<= 1) {
            #pragma unroll
            for (int r = 0; r < 4; ++r)
                psum[r] += __shfl_xor(psum[r], off);
        }
        #pragma unroll
        for (int r = 0; r < 4; ++r) lrow[r] += psum[r];

        #pragma unroll
        for (int r = 0; r < 4; ++r) {
            int row = kq * 4 + r;
            int c0 = r16 ^ ((row & 7) << 3);
            int c1 = (16 + r16) ^ ((row & 7) << 3);
            *(unsigned short*)(pl + row * 128 + c0 * 2) = f2bf(pv0[r]);
            *(unsigned short*)(pl + row * 128 + c1 * 2) = f2bf(pv1[r]);
        }
        short8 pa = *(const short8*)(pl + r16 * 128 + ((kq ^ (r16 & 7)) * 16));
        #pragma unroll
        for (int nn = 0; nn < 4; ++nn) {
            short8 vf = *(const short8*)(vp + (size_t)(nn * 16 + r16) * SEQ + k0 + kq * 8);
            po[nn] = __builtin_amdgcn_mfma_f32_16x16x32_bf16(pa, vf, po[nn], 0, 0, 0);
        }
    }

    const int b = bh >> 4, h = bh & 15;
    #pragma unroll
    for (int nn = 0; nn < 4; ++nn) {
        #pragma unroll
        for (int r = 0; r < 4; ++r) {
            int s = q0 + kq * 4 + r;
            float val = po[nn][r] / lrow[r];
            y[((size_t)(b * SEQ + s)) * E_DIM + h * HDIM + nn * 16 + r16] = f2bf(val);
        }
    }
}

// ---------------- output projection (fp32 out) ----------------
__global__ __launch_bounds__(256) void gemm_out(const unsigned short* __restrict__ yb,
        const unsigned short* __restrict__ wob, const float* __restrict__ bo,
        float* __restrict__ out) {
    __shared__ char lds[32768];
    const int m0 = blockIdx.x * 128;
    const int n0 = blockIdx.y * 128;
    f32x4 acc[4][4];
    #pragma unroll
    for (int m = 0; m < 4; ++m)
        #pragma unroll
        for (int n = 0; n < 4; ++n)
            acc[m][n] = (f32x4){0.f, 0.f, 0.f, 0.f};

    gemm_tile(yb, wob, m0, n0, acc, lds, lds + 16384);

    const int t = threadIdx.x;
    const int w = t >> 6, l = t & 63;
    const int r16 = l & 15, kq = l >> 4;
    const int wr = w >> 1, wc = w & 1;
    #pragma unroll
    for (int n = 0; n < 4; ++n) {
        int e = n0 + wc * 64 + n * 16 + r16;
        float bb = bo[e];
        #pragma unroll
        for (int m = 0; m < 4; ++m) {
            #pragma unroll
            for (int r = 0; r < 4; ++r) {
                int tok = m0 + wr * 64 + m * 16 + kq * 4 + r;
                out[(size_t)tok * E_DIM + e] = acc[m][n][r] + bb;
            }
        }
    }
}

extern "C" void kernel_launch(void* const* d_in, const int* in_sizes, int n_in,
                              void* d_out, int out_size, void* d_ws, size_t ws_size,
                              hipStream_t stream) {
    const float* x  = (const float*)d_in[0];
    const float* Wq = (const float*)d_in[1];
    const float* Wk = (const float*)d_in[2];
    const float* Wv = (const float*)d_in[3];
    const float* Wo = (const float*)d_in[4];
    const float* bq = (const float*)d_in[5];
    const float* bk = (const float*)d_in[6];
    const float* bv = (const float*)d_in[7];
    const float* bo = (const float*)d_in[8];
    float* out = (float*)d_out;

    char* ws = (char*)d_ws;
    unsigned short* xb  = (unsigned short*)(ws);                        // 8 MB
    unsigned short* wqb = (unsigned short*)(ws + ((size_t)8 << 20));    // 2 MB
    unsigned short* wkb = (unsigned short*)(ws + ((size_t)10 << 20));   // 2 MB
    unsigned short* wvb = (unsigned short*)(ws + ((size_t)12 << 20));   // 2 MB
    unsigned short* wob = (unsigned short*)(ws + ((size_t)14 << 20));   // 2 MB
    unsigned short* qw  = (unsigned short*)(ws + ((size_t)16 << 20));   // 8 MB
    unsigned short* kw  = (unsigned short*)(ws + ((size_t)24 << 20));   // 8 MB
    unsigned short* vTw = (unsigned short*)(ws + ((size_t)40 << 20));   // 8 MB
    unsigned short* yw  = (unsigned short*)(ws + ((size_t)48 << 20));   // 8 MB

    conv_f2b<<<4096, 256, 0, stream>>>(x, xb, MTOK * E_DIM / 4);
    conv_w4<<<dim3(1024, 4), 256, 0, stream>>>(Wq, Wk, Wv, Wo, wqb, wkb, wvb, wob);

    gemm8_qkv<<<dim3(16, 12), 512, 0, stream>>>(xb, wqb, wkb, wvb, bq, bk, bv, qw, kw, vTw);
    attn_swa<<<1024, 256, 0, stream>>>(qw, kw, vTw, yw);
    gemm_out<<<dim3(32, 8), 256, 0, stream>>>(yw, wob, bo, out);
}

// Round 3
// 177.311 us; speedup vs baseline: 1.1379x; 1.0604x over previous
//
#include <hip/hip_runtime.h>

#define E_DIM 1024
#define NHEAD 16
#define HDIM 64
#define SEQ 2048
#define NBATCH 2
#define WIN 256
#define MTOK (NBATCH * SEQ) // 4096
#define BKT 32              // K per pipeline tile in gemm8
#define NT (E_DIM / BKT)    // 32 tiles

typedef __attribute__((ext_vector_type(4))) float f32x4;
typedef __attribute__((ext_vector_type(8))) short short8;
typedef __attribute__((ext_vector_type(4))) unsigned short u16x4;

#define AS1 __attribute__((address_space(1)))
#define AS3 __attribute__((address_space(3)))

__device__ __forceinline__ void gll16(const void* g, void* l) {
    __builtin_amdgcn_global_load_lds((const AS1 void*)g, (AS3 void*)l, 16, 0, 0);
}

__device__ __forceinline__ unsigned short f2bf(float f) {
    union { float f; unsigned u; } a; a.f = f;
    unsigned r = a.u + 0x7fffu + ((a.u >> 16) & 1u);
    return (unsigned short)(r >> 16);
}

// ---------------- fp32 -> bf16 conversion (x) ----------------
__global__ __launch_bounds__(256) void conv_f2b(const float* __restrict__ src,
                                                unsigned short* __restrict__ dst, int n4) {
    int i = blockIdx.x * 256 + threadIdx.x;
    int stride = gridDim.x * 256;
    for (; i < n4; i += stride) {
        float4 v = ((const float4*)src)[i];
        u16x4 o;
        o[0] = f2bf(v.x); o[1] = f2bf(v.y); o[2] = f2bf(v.z); o[3] = f2bf(v.w);
        ((u16x4*)dst)[i] = o;
    }
}

// ---------------- fp32 -> bf16 for the 4 weight matrices, one launch ----------------
__global__ __launch_bounds__(256) void conv_w4(const float* __restrict__ w0, const float* __restrict__ w1,
                                               const float* __restrict__ w2, const float* __restrict__ w3,
                                               unsigned short* __restrict__ o0, unsigned short* __restrict__ o1,
                                               unsigned short* __restrict__ o2, unsigned short* __restrict__ o3) {
    const int m = blockIdx.y;
    const float* src = (m == 0) ? w0 : (m == 1) ? w1 : (m == 2) ? w2 : w3;
    unsigned short* dst = (m == 0) ? o0 : (m == 1) ? o1 : (m == 2) ? o2 : o3;
    int i = blockIdx.x * 256 + threadIdx.x;
    float4 v = ((const float4*)src)[i];
    u16x4 o;
    o[0] = f2bf(v.x); o[1] = f2bf(v.y); o[2] = f2bf(v.z); o[3] = f2bf(v.w);
    ((u16x4*)dst)[i] = o;
}

// ---------------- 8-phase-style QKV GEMM (now with T2 both-sides swizzle) ----------------
// C(256x256) = A[m0:,:] @ Bw[nb:,:]^T. 512 threads = 8 waves (2M x 4N), per-wave C = 128x64.
// LDS slot swizzle: phys_slot = logical_slot ^ ((row>>1)&3), applied on the global
// SOURCE address (gll writes linearly) and on the ds_read address (rule 21).
__global__ __launch_bounds__(512, 2) void gemm8_qkv(const unsigned short* __restrict__ xb,
        const unsigned short* __restrict__ wqb, const unsigned short* __restrict__ wkb,
        const unsigned short* __restrict__ wvb,
        const float* __restrict__ bq, const float* __restrict__ bk, const float* __restrict__ bv,
        unsigned short* __restrict__ qo, unsigned short* __restrict__ ko,
        unsigned short* __restrict__ vTo) {
    __shared__ char lds[131072];
    const int tid = threadIdx.x;
    const int w = tid >> 6, l = tid & 63;
    const int r16 = l & 15, kq = l >> 4;
    const int wm = w >> 2, wn = w & 3;
    const int m0 = blockIdx.x * 256;
    const int by = blockIdx.y;            // 0..11
    const int mat = by >> 2;              // 0:Q 1:K 2:V
    const int nb = (by & 3) * 256;
    const unsigned short* Bw = (mat == 0) ? wqb : (mat == 1) ? wkb : wvb;

    // staging: unit = one 256x32 k-panel (16KB); lane (srow, sslot)
    const int srow = tid >> 2;            // 0..127 (plus +128 half)
    const int sslot = tid & 3;            // logical 16B slot in 64B row
    const int fsw = (srow >> 1) & 3;      // same for row srow and row 128+srow
    const int gslot = (sslot ^ fsw) * 8;  // pre-swizzled source slot (elements)
    const unsigned short* aSrc0 = xb + (size_t)(m0 + srow) * E_DIM + gslot;
    const unsigned short* aSrc1 = aSrc0 + (size_t)128 * E_DIM;
    const unsigned short* bSrc0 = Bw + (size_t)(nb + srow) * E_DIM + gslot;
    const unsigned short* bSrc1 = bSrc0 + (size_t)128 * E_DIM;
    const int dstOff = w * 1024;          // wave-uniform chunk base (bytes)

#define STAGE_A(t) { char* d_ = lds + ((t) & 3) * 32768 + dstOff; \
                     gll16(aSrc0 + (t) * BKT, d_); gll16(aSrc1 + (t) * BKT, d_ + 8192); }
#define STAGE_B(t) { char* d_ = lds + ((t) & 3) * 32768 + 16384 + dstOff; \
                     gll16(bSrc0 + (t) * BKT, d_); gll16(bSrc1 + (t) * BKT, d_ + 8192); }

    f32x4 acc[8][4];
    #pragma unroll
    for (int m = 0; m < 8; ++m)
        #pragma unroll
        for (int n = 0; n < 4; ++n)
            acc[m][n] = (f32x4){0.f, 0.f, 0.f, 0.f};

    STAGE_A(0); STAGE_B(0); STAGE_A(1); STAGE_B(1);

    const int fs = (r16 >> 1) & 3;        // read-side swizzle, frag-row-independent
    const int rdoff = (kq ^ fs) * 16;     // byte offset of the 16B phys slot

    for (int t = 0; t < NT; ++t) {
        if (t < NT - 1) { asm volatile("s_waitcnt vmcnt(4)" ::: "memory"); }
        else            { asm volatile("s_waitcnt vmcnt(0)" ::: "memory"); }
        __builtin_amdgcn_sched_barrier(0);
        __builtin_amdgcn_s_barrier();
        __builtin_amdgcn_sched_barrier(0);
        char* la = lds + (t & 3) * 32768;
        char* lb = la + 16384;
        // ---- phase 0 ----
        short8 bfr[4], af[4];
        #pragma unroll
        for (int n = 0; n < 4; ++n)
            bfr[n] = *(const short8*)(lb + (wn * 64 + n * 16 + r16) * 64 + rdoff);
        #pragma unroll
        for (int j = 0; j < 4; ++j)
            af[j] = *(const short8*)(la + (wm * 128 + j * 16 + r16) * 64 + rdoff);
        if (t + 2 < NT) STAGE_A(t + 2);
        __builtin_amdgcn_s_barrier();
        __builtin_amdgcn_sched_barrier(0);
        __builtin_amdgcn_s_setprio(1);
        #pragma unroll
        for (int j = 0; j < 4; ++j)
            #pragma unroll
            for (int n = 0; n < 4; ++n)
                acc[j][n] = __builtin_amdgcn_mfma_f32_16x16x32_bf16(af[j], bfr[n], acc[j][n], 0, 0, 0);
        __builtin_amdgcn_s_setprio(0);
        // ---- phase 1 ----
        short8 af2[4];
        #pragma unroll
        for (int j = 0; j < 4; ++j)
            af2[j] = *(const short8*)(la + (wm * 128 + (4 + j) * 16 + r16) * 64 + rdoff);
        if (t + 2 < NT) STAGE_B(t + 2);
        __builtin_amdgcn_s_barrier();
        __builtin_amdgcn_sched_barrier(0);
        __builtin_amdgcn_s_setprio(1);
        #pragma unroll
        for (int j = 0; j < 4; ++j)
            #pragma unroll
            for (int n = 0; n < 4; ++n)
                acc[4 + j][n] = __builtin_amdgcn_mfma_f32_16x16x32_bf16(af2[j], bfr[n], acc[4 + j][n], 0, 0, 0);
        __builtin_amdgcn_s_setprio(0);
    }
#undef STAGE_A
#undef STAGE_B

    const float* bias = (mat == 0) ? bq : (mat == 1) ? bk : bv;
    const float scale = (mat == 0) ? 0.125f : 1.0f;
    #pragma unroll
    for (int n = 0; n < 4; ++n) {
        int e = nb + wn * 64 + n * 16 + r16;
        float bb = bias[e];
        int h = e >> 6, d = e & 63;
        #pragma unroll
        for (int m = 0; m < 8; ++m) {
            int tok = m0 + wm * 128 + m * 16 + kq * 4;
            int b = tok >> 11, s = tok & (SEQ - 1);
            if (mat == 2) {
                u16x4 o;
                #pragma unroll
                for (int r = 0; r < 4; ++r) o[r] = f2bf(acc[m][n][r] + bb);
                *(u16x4*)(vTo + ((size_t)(b * NHEAD + h) * HDIM + d) * SEQ + s) = o;
            } else {
                unsigned short* dst = (mat == 0) ? qo : ko;
                #pragma unroll
                for (int r = 0; r < 4; ++r) {
                    float val = (acc[m][n][r] + bb) * scale;
                    dst[((size_t)(b * NHEAD + h) * SEQ + s + r) * HDIM + d] = f2bf(val);
                }
            }
        }
    }
}

// ---------------- shared GEMM mainloop (128x128, used by gemm_out) ----------------
__device__ __forceinline__ void gemm_tile(const unsigned short* __restrict__ A,
                                          const unsigned short* __restrict__ Bw,
                                          int m0, int n0,
                                          f32x4 acc[4][4], char* ldsA, char* ldsB) {
    const int t = threadIdx.x;
    const int w = t >> 6, l = t & 63;
    const int r16 = l & 15, kq = l >> 4;
    const int wr = w >> 1, wc = w & 1;
    const int srow = l >> 3, ps = l & 7;

    for (int kt = 0; kt < E_DIM / 64; ++kt) {
        #pragma unroll
        for (int c = 0; c < 4; ++c) {
            int chunk = w * 4 + c;
            int row = chunk * 8 + srow;
            int kslot = ps ^ (row & 7);
            gll16(A  + (size_t)(m0 + row) * E_DIM + kt * 64 + kslot * 8, ldsA + chunk * 1024);
            gll16(Bw + (size_t)(n0 + row) * E_DIM + kt * 64 + kslot * 8, ldsB + chunk * 1024);
        }
        __syncthreads();
        #pragma unroll
        for (int kk = 0; kk < 2; ++kk) {
            short8 af[4], bfr[4];
            #pragma unroll
            for (int m = 0; m < 4; ++m) {
                int rr = wr * 64 + m * 16 + r16;
                int c = kk * 4 + kq;
                af[m] = *(const short8*)(ldsA + rr * 128 + ((c ^ (rr & 7)) * 16));
            }
            #pragma unroll
            for (int n = 0; n < 4; ++n) {
                int rr = wc * 64 + n * 16 + r16;
                int c = kk * 4 + kq;
                bfr[n] = *(const short8*)(ldsB + rr * 128 + ((c ^ (rr & 7)) * 16));
            }
            #pragma unroll
            for (int m = 0; m < 4; ++m)
                #pragma unroll
                for (int n = 0; n < 4; ++n)
                    acc[m][n] = __builtin_amdgcn_mfma_f32_16x16x32_bf16(af[m], bfr[n], acc[m][n], 0, 0, 0);
        }
        __syncthreads();
    }
}

// ---------------- sliding-window flash attention: 32 q-rows per wave ----------------
__global__ __launch_bounds__(256) void attn_swa(const unsigned short* __restrict__ q,
                                                const unsigned short* __restrict__ k,
                                                const unsigned short* __restrict__ vT,
                                                unsigned short* __restrict__ y) {
    __shared__ char plds[4 * 4096];       // per wave: 2 m-frags x [16][64] bf16 slot-swizzled
    const int t = threadIdx.x;
    const int w = t >> 6, l = t & 63;
    const int r16 = l & 15, kq = l >> 4;
    const int wid = blockIdx.x * 4 + w;   // 0..2047
    const int bh = wid >> 6;              // 64 waves per (b,h)
    const int q0 = (wid & 63) * 32;
    const unsigned short* qp = q + (size_t)bh * SEQ * HDIM;
    const unsigned short* kp = k + (size_t)bh * SEQ * HDIM;
    const unsigned short* vp = vT + (size_t)bh * HDIM * SEQ;
    char* pl = plds + w * 4096;

    short8 qf[2][2];
    #pragma unroll
    for (int mf = 0; mf < 2; ++mf) {
        const unsigned short* qr = qp + (q0 + mf * 16 + r16) * HDIM + kq * 8;
        qf[mf][0] = *(const short8*)(qr);
        qf[mf][1] = *(const short8*)(qr + 32);
    }

    f32x4 po[2][4];
    float mrow[2][4], lrow[2][4];
    #pragma unroll
    for (int mf = 0; mf < 2; ++mf) {
        #pragma unroll
        for (int nn = 0; nn < 4; ++nn) po[mf][nn] = (f32x4){0.f, 0.f, 0.f, 0.f};
        #pragma unroll
        for (int r = 0; r < 4; ++r) { mrow[mf][r] = -1e30f; lrow[mf][r] = 0.f; }
    }

    const int kstart = (q0 >= WIN) ? (q0 - WIN) : 0;   // q0, WIN multiples of 32
    for (int k0 = kstart; k0 <= q0 + 31; k0 += 32) {
        short8 kf[2][2];
        #pragma unroll
        for (int n = 0; n < 2; ++n) {
            const unsigned short* kr = kp + (size_t)(k0 + n * 16 + r16) * HDIM + kq * 8;
            kf[n][0] = *(const short8*)(kr);
            kf[n][1] = *(const short8*)(kr + 32);
        }
        f32x4 sc[2][2];
        #pragma unroll
        for (int mf = 0; mf < 2; ++mf)
            #pragma unroll
            for (int n = 0; n < 2; ++n) {
                f32x4 z = {0.f, 0.f, 0.f, 0.f};
                z = __builtin_amdgcn_mfma_f32_16x16x32_bf16(qf[mf][0], kf[n][0], z, 0, 0, 0);
                sc[mf][n] = __builtin_amdgcn_mfma_f32_16x16x32_bf16(qf[mf][1], kf[n][1], z, 0, 0, 0);
            }
        float tmax[2][4];
        #pragma unroll
        for (int mf = 0; mf < 2; ++mf)
            #pragma unroll
            for (int r = 0; r < 4; ++r) {
                int qrow = q0 + mf * 16 + kq * 4 + r;
                int key0 = k0 + r16;
                int key1 = key0 + 16;
                if (!(key0 <= qrow && key0 >= qrow - WIN)) sc[mf][0][r] = -1e30f;
                if (!(key1 <= qrow && key1 >= qrow - WIN)) sc[mf][1][r] = -1e30f;
                tmax[mf][r] = fmaxf(sc[mf][0][r], sc[mf][1][r]);
            }
        #pragma unroll
        for (int off = 1; off < 16; off <<= 1)
            #pragma unroll
            for (int mf = 0; mf < 2; ++mf)
                #pragma unroll
                for (int r = 0; r < 4; ++r)
                    tmax[mf][r] = fmaxf(tmax[mf][r], __shfl_xor(tmax[mf][r], off));
        float pv[2][2][4], psum[2][4];
        #pragma unroll
        for (int mf = 0; mf < 2; ++mf)
            #pragma unroll
            for (int r = 0; r < 4; ++r) {
                float mnew = fmaxf(mrow[mf][r], tmax[mf][r]);
                float resc = __expf(mrow[mf][r] - mnew);
                mrow[mf][r] = mnew;
                lrow[mf][r] *= resc;
                po[mf][0][r] *= resc; po[mf][1][r] *= resc;
                po[mf][2][r] *= resc; po[mf][3][r] *= resc;
                float p0 = (sc[mf][0][r] > -1e29f) ? __expf(sc[mf][0][r] - mnew) : 0.f;
                float p1 = (sc[mf][1][r] > -1e29f) ? __expf(sc[mf][1][r] - mnew) : 0.f;
                pv[mf][0][r] = p0; pv[mf][1][r] = p1;
                psum[mf][r] = p0 + p1;
            }
        #pragma unroll
        for (int off = 1; off < 16; off <<= 1)
            #pragma unroll
            for (int mf = 0; mf < 2; ++mf)
                #pragma unroll
                for (int r = 0; r < 4; ++r)
                    psum[mf][r] += __shfl_xor(psum[mf][r], off);
        #pragma unroll
        for (int mf = 0; mf < 2; ++mf)
            #pragma unroll
            for (int r = 0; r < 4; ++r) lrow[mf][r] += psum[mf][r];

        // P (C-layout) -> LDS with 16B-slot XOR swizzle -> A-frag, per m-frag buffer
        #pragma unroll
        for (int mf = 0; mf < 2; ++mf)
            #pragma unroll
            for (int r = 0; r < 4; ++r) {
                int row = kq * 4 + r;
                int c0 = r16 ^ ((row & 7) << 3);
                int c1 = (16 + r16) ^ ((row & 7) << 3);
                *(unsigned short*)(pl + mf * 2048 + row * 128 + c0 * 2) = f2bf(pv[mf][0][r]);
                *(unsigned short*)(pl + mf * 2048 + row * 128 + c1 * 2) = f2bf(pv[mf][1][r]);
            }
        short8 pa[2];
        #pragma unroll
        for (int mf = 0; mf < 2; ++mf)
            pa[mf] = *(const short8*)(pl + mf * 2048 + r16 * 128 + ((kq ^ (r16 & 7)) * 16));
        #pragma unroll
        for (int nn = 0; nn < 4; ++nn) {
            short8 vf = *(const short8*)(vp + (size_t)(nn * 16 + r16) * SEQ + k0 + kq * 8);
            po[0][nn] = __builtin_amdgcn_mfma_f32_16x16x32_bf16(pa[0], vf, po[0][nn], 0, 0, 0);
            po[1][nn] = __builtin_amdgcn_mfma_f32_16x16x32_bf16(pa[1], vf, po[1][nn], 0, 0, 0);
        }
    }

    const int b = bh >> 4, h = bh & 15;
    #pragma unroll
    for (int mf = 0; mf < 2; ++mf)
        #pragma unroll
        for (int nn = 0; nn < 4; ++nn)
            #pragma unroll
            for (int r = 0; r < 4; ++r) {
                int s = q0 + mf * 16 + kq * 4 + r;
                float val = po[mf][nn][r] / lrow[mf][r];
                y[((size_t)(b * SEQ + s)) * E_DIM + h * HDIM + nn * 16 + r16] = f2bf(val);
            }
}

// ---------------- output projection (fp32 out) ----------------
__global__ __launch_bounds__(256) void gemm_out(const unsigned short* __restrict__ yb,
        const unsigned short* __restrict__ wob, const float* __restrict__ bo,
        float* __restrict__ out) {
    __shared__ char lds[32768];
    const int m0 = blockIdx.x * 128;
    const int n0 = blockIdx.y * 128;
    f32x4 acc[4][4];
    #pragma unroll
    for (int m = 0; m < 4; ++m)
        #pragma unroll
        for (int n = 0; n < 4; ++n)
            acc[m][n] = (f32x4){0.f, 0.f, 0.f, 0.f};

    gemm_tile(yb, wob, m0, n0, acc, lds, lds + 16384);

    const int t = threadIdx.x;
    const int w = t >> 6, l = t & 63;
    const int r16 = l & 15, kq = l >> 4;
    const int wr = w >> 1, wc = w & 1;
    #pragma unroll
    for (int n = 0; n < 4; ++n) {
        int e = n0 + wc * 64 + n * 16 + r16;
        float bb = bo[e];
        #pragma unroll
        for (int m = 0; m < 4; ++m) {
            #pragma unroll
            for (int r = 0; r < 4; ++r) {
                int tok = m0 + wr * 64 + m * 16 + kq * 4 + r;
                out[(size_t)tok * E_DIM + e] = acc[m][n][r] + bb;
            }
        }
    }
}

extern "C" void kernel_launch(void* const* d_in, const int* in_sizes, int n_in,
                              void* d_out, int out_size, void* d_ws, size_t ws_size,
                              hipStream_t stream) {
    const float* x  = (const float*)d_in[0];
    const float* Wq = (const float*)d_in[1];
    const float* Wk = (const float*)d_in[2];
    const float* Wv = (const float*)d_in[3];
    const float* Wo = (const float*)d_in[4];
    const float* bq = (const float*)d_in[5];
    const float* bk = (const float*)d_in[6];
    const float* bv = (const float*)d_in[7];
    const float* bo = (const float*)d_in[8];
    float* out = (float*)d_out;

    char* ws = (char*)d_ws;
    unsigned short* xb  = (unsigned short*)(ws);                        // 8 MB
    unsigned short* wqb = (unsigned short*)(ws + ((size_t)8 << 20));    // 2 MB
    unsigned short* wkb = (unsigned short*)(ws + ((size_t)10 << 20));   // 2 MB
    unsigned short* wvb = (unsigned short*)(ws + ((size_t)12 << 20));   // 2 MB
    unsigned short* wob = (unsigned short*)(ws + ((size_t)14 << 20));   // 2 MB
    unsigned short* qw  = (unsigned short*)(ws + ((size_t)16 << 20));   // 8 MB
    unsigned short* kw  = (unsigned short*)(ws + ((size_t)24 << 20));   // 8 MB
    unsigned short* vTw = (unsigned short*)(ws + ((size_t)40 << 20));   // 8 MB
    unsigned short* yw  = (unsigned short*)(ws + ((size_t)48 << 20));   // 8 MB

    conv_f2b<<<4096, 256, 0, stream>>>(x, xb, MTOK * E_DIM / 4);
    conv_w4<<<dim3(1024, 4), 256, 0, stream>>>(Wq, Wk, Wv, Wo, wqb, wkb, wvb, wob);

    gemm8_qkv<<<dim3(16, 12), 512, 0, stream>>>(xb, wqb, wkb, wvb, bq, bk, bv, qw, kw, vTw);
    attn_swa<<<512, 256, 0, stream>>>(qw, kw, vTw, yw);
    gemm_out<<<dim3(32, 8), 256, 0, stream>>>(yw, wob, bo, out);
}

// Round 4
// 166.066 us; speedup vs baseline: 1.2150x; 1.0677x over previous
//
#include <hip/hip_runtime.h>

#define E_DIM 1024
#define NHEAD 16
#define HDIM 64
#define SEQ 2048
#define NBATCH 2
#define WIN 256
#define MTOK (NBATCH * SEQ) // 4096
#define BKT 32              // K per pipeline tile
#define NT (E_DIM / BKT)    // 32 tiles

typedef __attribute__((ext_vector_type(4))) float f32x4;
typedef __attribute__((ext_vector_type(8))) short short8;
typedef __attribute__((ext_vector_type(4))) unsigned short u16x4;

#define AS1 __attribute__((address_space(1)))
#define AS3 __attribute__((address_space(3)))

__device__ __forceinline__ void gll16(const void* g, void* l) {
    __builtin_amdgcn_global_load_lds((const AS1 void*)g, (AS3 void*)l, 16, 0, 0);
}

__device__ __forceinline__ unsigned short f2bf(float f) {
    union { float f; unsigned u; } a; a.f = f;
    unsigned r = a.u + 0x7fffu + ((a.u >> 16) & 1u);
    return (unsigned short)(r >> 16);
}

// ---------------- fused fp32 -> bf16 conversion: x (4 segs) + 4 weights ----------------
__global__ __launch_bounds__(256) void conv_all(const float* __restrict__ x,
        const float* __restrict__ w0, const float* __restrict__ w1,
        const float* __restrict__ w2, const float* __restrict__ w3,
        unsigned short* __restrict__ xo,
        unsigned short* __restrict__ o0, unsigned short* __restrict__ o1,
        unsigned short* __restrict__ o2, unsigned short* __restrict__ o3) {
    const int seg = blockIdx.y;   // 0..3: x quarters; 4..7: weights
    const float* src;
    unsigned short* dst;
    if (seg < 4) { src = x + (size_t)seg * 1048576; dst = xo + (size_t)seg * 1048576; }
    else {
        src = (seg == 4) ? w0 : (seg == 5) ? w1 : (seg == 6) ? w2 : w3;
        dst = (seg == 4) ? o0 : (seg == 5) ? o1 : (seg == 6) ? o2 : o3;
    }
    int i = blockIdx.x * 256 + threadIdx.x;   // grid.x = 1024 -> 262144 float4 per seg
    float4 v = ((const float4*)src)[i];
    u16x4 o;
    o[0] = f2bf(v.x); o[1] = f2bf(v.y); o[2] = f2bf(v.z); o[3] = f2bf(v.w);
    ((u16x4*)dst)[i] = o;
}

// ---------------- QKV GEMM: single-barrier-per-tile, 4-deep LDS pipeline ----------------
// C(256x256) = A[m0:,:] @ Bw[nb:,:]^T. 512 threads = 8 waves (2M x 4N), per-wave C = 128x64.
// Per tile: vmcnt(4) + barrier, 12 ds_read_b128 up-front, stage tile t+2, 32 MFMA.
// LDS slot swizzle phys_slot = slot ^ ((row>>1)&3) on BOTH source addr and ds_read addr.
__global__ __launch_bounds__(512, 2) void gemm8_qkv(const unsigned short* __restrict__ xb,
        const unsigned short* __restrict__ wqb, const unsigned short* __restrict__ wkb,
        const unsigned short* __restrict__ wvb,
        const float* __restrict__ bq, const float* __restrict__ bk, const float* __restrict__ bv,
        unsigned short* __restrict__ qo, unsigned short* __restrict__ ko,
        unsigned short* __restrict__ vTo) {
    __shared__ char lds[131072];
    const int tid = threadIdx.x;
    const int w = tid >> 6, l = tid & 63;
    const int r16 = l & 15, kq = l >> 4;
    const int wm = w >> 2, wn = w & 3;
    const int m0 = blockIdx.x * 256;
    const int by = blockIdx.y;            // 0..11
    const int mat = by >> 2;              // 0:Q 1:K 2:V
    const int nb = (by & 3) * 256;
    const unsigned short* Bw = (mat == 0) ? wqb : (mat == 1) ? wkb : wvb;

    const int srow = tid >> 2;            // 0..127 (plus +128 half)
    const int sslot = tid & 3;
    const int fsw = (srow >> 1) & 3;
    const int gslot = (sslot ^ fsw) * 8;  // pre-swizzled source slot (elements)
    const unsigned short* aSrc0 = xb + (size_t)(m0 + srow) * E_DIM + gslot;
    const unsigned short* aSrc1 = aSrc0 + (size_t)128 * E_DIM;
    const unsigned short* bSrc0 = Bw + (size_t)(nb + srow) * E_DIM + gslot;
    const unsigned short* bSrc1 = bSrc0 + (size_t)128 * E_DIM;
    const int dstOff = w * 1024;

#define STAGE_A(t) { char* d_ = lds + ((t) & 3) * 32768 + dstOff; \
                     gll16(aSrc0 + (t) * BKT, d_); gll16(aSrc1 + (t) * BKT, d_ + 8192); }
#define STAGE_B(t) { char* d_ = lds + ((t) & 3) * 32768 + 16384 + dstOff; \
                     gll16(bSrc0 + (t) * BKT, d_); gll16(bSrc1 + (t) * BKT, d_ + 8192); }

    f32x4 acc[8][4];
    #pragma unroll
    for (int m = 0; m < 8; ++m)
        #pragma unroll
        for (int n = 0; n < 4; ++n)
            acc[m][n] = (f32x4){0.f, 0.f, 0.f, 0.f};

    STAGE_A(0); STAGE_B(0); STAGE_A(1); STAGE_B(1);

    const int fs = (r16 >> 1) & 3;
    const int rdoff = (kq ^ fs) * 16;

    for (int t = 0; t < NT; ++t) {
        if (t < NT - 1) { asm volatile("s_waitcnt vmcnt(4)" ::: "memory"); }
        else            { asm volatile("s_waitcnt vmcnt(0)" ::: "memory"); }
        __builtin_amdgcn_sched_barrier(0);
        __builtin_amdgcn_s_barrier();
        __builtin_amdgcn_sched_barrier(0);
        char* la = lds + (t & 3) * 32768;
        char* lb = la + 16384;
        // all 12 fragment reads up-front (compiler emits progressive lgkmcnt)
        short8 bfr[4], af[8];
        #pragma unroll
        for (int n = 0; n < 4; ++n)
            bfr[n] = *(const short8*)(lb + (wn * 64 + n * 16 + r16) * 64 + rdoff);
        #pragma unroll
        for (int j = 0; j < 8; ++j)
            af[j] = *(const short8*)(la + (wm * 128 + j * 16 + r16) * 64 + rdoff);
        // stage tile t+2 (slot (t+2)&3 — safe under max 1-tile wave skew)
        if (t + 2 < NT) { STAGE_A(t + 2); STAGE_B(t + 2); }
        __builtin_amdgcn_s_setprio(1);
        #pragma unroll
        for (int j = 0; j < 8; ++j)
            #pragma unroll
            for (int n = 0; n < 4; ++n)
                acc[j][n] = __builtin_amdgcn_mfma_f32_16x16x32_bf16(af[j], bfr[n], acc[j][n], 0, 0, 0);
        __builtin_amdgcn_s_setprio(0);
    }
#undef STAGE_A
#undef STAGE_B

    const float* bias = (mat == 0) ? bq : (mat == 1) ? bk : bv;
    const float scale = (mat == 0) ? 0.125f : 1.0f;   // D^-0.5 folded into Q
    #pragma unroll
    for (int n = 0; n < 4; ++n) {
        int e = nb + wn * 64 + n * 16 + r16;
        float bb = bias[e];
        int h = e >> 6, d = e & 63;
        #pragma unroll
        for (int m = 0; m < 8; ++m) {
            int tok = m0 + wm * 128 + m * 16 + kq * 4;
            int b = tok >> 11, s = tok & (SEQ - 1);
            if (mat == 2) {
                u16x4 o;
                #pragma unroll
                for (int r = 0; r < 4; ++r) o[r] = f2bf(acc[m][n][r] + bb);
                *(u16x4*)(vTo + ((size_t)(b * NHEAD + h) * HDIM + d) * SEQ + s) = o;
            } else {
                unsigned short* dst = (mat == 0) ? qo : ko;
                #pragma unroll
                for (int r = 0; r < 4; ++r) {
                    float val = (acc[m][n][r] + bb) * scale;
                    dst[((size_t)(b * NHEAD + h) * SEQ + s + r) * HDIM + d] = f2bf(val);
                }
            }
        }
    }
}

// ---------------- output projection: same structure at 128x128, 4 waves ----------------
__global__ __launch_bounds__(256, 2) void gemm_out(const unsigned short* __restrict__ yb,
        const unsigned short* __restrict__ wob, const float* __restrict__ bo,
        float* __restrict__ out) {
    __shared__ char lds[65536];           // 4 slots x (A 8KB + B 8KB)
    const int tid = threadIdx.x;
    const int w = tid >> 6, l = tid & 63;
    const int r16 = l & 15, kq = l >> 4;
    const int wr = w >> 1, wc = w & 1;
    const int m0 = blockIdx.x * 128;
    const int n0 = blockIdx.y * 128;

    const int srow = tid >> 2;            // 0..63 within 128-row panel halves
    const int sslot = tid & 3;
    const int fsw = (srow >> 1) & 3;
    const int gslot = (sslot ^ fsw) * 8;
    const unsigned short* aSrc0 = yb + (size_t)(m0 + srow) * E_DIM + gslot;
    const unsigned short* aSrc1 = aSrc0 + (size_t)64 * E_DIM;
    const unsigned short* bSrc0 = wob + (size_t)(n0 + srow) * E_DIM + gslot;
    const unsigned short* bSrc1 = bSrc0 + (size_t)64 * E_DIM;
    const int dstOff = w * 1024;

#define STAGE_A(t) { char* d_ = lds + ((t) & 3) * 16384 + dstOff; \
                     gll16(aSrc0 + (t) * BKT, d_); gll16(aSrc1 + (t) * BKT, d_ + 4096); }
#define STAGE_B(t) { char* d_ = lds + ((t) & 3) * 16384 + 8192 + dstOff; \
                     gll16(bSrc0 + (t) * BKT, d_); gll16(bSrc1 + (t) * BKT, d_ + 4096); }

    f32x4 acc[4][4];
    #pragma unroll
    for (int m = 0; m < 4; ++m)
        #pragma unroll
        for (int n = 0; n < 4; ++n)
            acc[m][n] = (f32x4){0.f, 0.f, 0.f, 0.f};

    STAGE_A(0); STAGE_B(0); STAGE_A(1); STAGE_B(1);

    const int fs = (r16 >> 1) & 3;
    const int rdoff = (kq ^ fs) * 16;

    for (int t = 0; t < NT; ++t) {
        if (t < NT - 1) { asm volatile("s_waitcnt vmcnt(4)" ::: "memory"); }
        else            { asm volatile("s_waitcnt vmcnt(0)" ::: "memory"); }
        __builtin_amdgcn_sched_barrier(0);
        __builtin_amdgcn_s_barrier();
        __builtin_amdgcn_sched_barrier(0);
        char* la = lds + (t & 3) * 16384;
        char* lb = la + 8192;
        short8 bfr[4], af[4];
        #pragma unroll
        for (int n = 0; n < 4; ++n)
            bfr[n] = *(const short8*)(lb + (wc * 64 + n * 16 + r16) * 64 + rdoff);
        #pragma unroll
        for (int m = 0; m < 4; ++m)
            af[m] = *(const short8*)(la + (wr * 64 + m * 16 + r16) * 64 + rdoff);
        if (t + 2 < NT) { STAGE_A(t + 2); STAGE_B(t + 2); }
        __builtin_amdgcn_s_setprio(1);
        #pragma unroll
        for (int m = 0; m < 4; ++m)
            #pragma unroll
            for (int n = 0; n < 4; ++n)
                acc[m][n] = __builtin_amdgcn_mfma_f32_16x16x32_bf16(af[m], bfr[n], acc[m][n], 0, 0, 0);
        __builtin_amdgcn_s_setprio(0);
    }
#undef STAGE_A
#undef STAGE_B

    #pragma unroll
    for (int n = 0; n < 4; ++n) {
        int e = n0 + wc * 64 + n * 16 + r16;
        float bb = bo[e];
        #pragma unroll
        for (int m = 0; m < 4; ++m) {
            #pragma unroll
            for (int r = 0; r < 4; ++r) {
                int tok = m0 + wr * 64 + m * 16 + kq * 4 + r;
                out[(size_t)tok * E_DIM + e] = acc[m][n][r] + bb;
            }
        }
    }
}

// ---------------- sliding-window flash attention: 32 q-rows per wave ----------------
__global__ __launch_bounds__(256) void attn_swa(const unsigned short* __restrict__ q,
                                                const unsigned short* __restrict__ k,
                                                const unsigned short* __restrict__ vT,
                                                unsigned short* __restrict__ y) {
    __shared__ char plds[4 * 4096];
    const int t = threadIdx.x;
    const int w = t >> 6, l = t & 63;
    const int r16 = l & 15, kq = l >> 4;
    const int wid = blockIdx.x * 4 + w;
    const int bh = wid >> 6;
    const int q0 = (wid & 63) * 32;
    const unsigned short* qp = q + (size_t)bh * SEQ * HDIM;
    const unsigned short* kp = k + (size_t)bh * SEQ * HDIM;
    const unsigned short* vp = vT + (size_t)bh * HDIM * SEQ;
    char* pl = plds + w * 4096;

    short8 qf[2][2];
    #pragma unroll
    for (int mf = 0; mf < 2; ++mf) {
        const unsigned short* qr = qp + (q0 + mf * 16 + r16) * HDIM + kq * 8;
        qf[mf][0] = *(const short8*)(qr);
        qf[mf][1] = *(const short8*)(qr + 32);
    }

    f32x4 po[2][4];
    float mrow[2][4], lrow[2][4];
    #pragma unroll
    for (int mf = 0; mf < 2; ++mf) {
        #pragma unroll
        for (int nn = 0; nn < 4; ++nn) po[mf][nn] = (f32x4){0.f, 0.f, 0.f, 0.f};
        #pragma unroll
        for (int r = 0; r < 4; ++r) { mrow[mf][r] = -1e30f; lrow[mf][r] = 0.f; }
    }

    const int kstart = (q0 >= WIN) ? (q0 - WIN) : 0;
    for (int k0 = kstart; k0 <= q0 + 31; k0 += 32) {
        short8 kf[2][2];
        #pragma unroll
        for (int n = 0; n < 2; ++n) {
            const unsigned short* kr = kp + (size_t)(k0 + n * 16 + r16) * HDIM + kq * 8;
            kf[n][0] = *(const short8*)(kr);
            kf[n][1] = *(const short8*)(kr + 32);
        }
        f32x4 sc[2][2];
        #pragma unroll
        for (int mf = 0; mf < 2; ++mf)
            #pragma unroll
            for (int n = 0; n < 2; ++n) {
                f32x4 z = {0.f, 0.f, 0.f, 0.f};
                z = __builtin_amdgcn_mfma_f32_16x16x32_bf16(qf[mf][0], kf[n][0], z, 0, 0, 0);
                sc[mf][n] = __builtin_amdgcn_mfma_f32_16x16x32_bf16(qf[mf][1], kf[n][1], z, 0, 0, 0);
            }
        float tmax[2][4];
        #pragma unroll
        for (int mf = 0; mf < 2; ++mf)
            #pragma unroll
            for (int r = 0; r < 4; ++r) {
                int qrow = q0 + mf * 16 + kq * 4 + r;
                int key0 = k0 + r16;
                int key1 = key0 + 16;
                if (!(key0 <= qrow && key0 >= qrow - WIN)) sc[mf][0][r] = -1e30f;
                if (!(key1 <= qrow && key1 >= qrow - WIN)) sc[mf][1][r] = -1e30f;
                tmax[mf][r] = fmaxf(sc[mf][0][r], sc[mf][1][r]);
            }
        #pragma unroll
        for (int off = 1; off < 16; off <<= 1)
            #pragma unroll
            for (int mf = 0; mf < 2; ++mf)
                #pragma unroll
                for (int r = 0; r < 4; ++r)
                    tmax[mf][r] = fmaxf(tmax[mf][r], __shfl_xor(tmax[mf][r], off));
        float pv[2][2][4], psum[2][4];
        #pragma unroll
        for (int mf = 0; mf < 2; ++mf)
            #pragma unroll
            for (int r = 0; r < 4; ++r) {
                float mnew = fmaxf(mrow[mf][r], tmax[mf][r]);
                float resc = __expf(mrow[mf][r] - mnew);
                mrow[mf][r] = mnew;
                lrow[mf][r] *= resc;
                po[mf][0][r] *= resc; po[mf][1][r] *= resc;
                po[mf][2][r] *= resc; po[mf][3][r] *= resc;
                float p0 = (sc[mf][0][r] > -1e29f) ? __expf(sc[mf][0][r] - mnew) : 0.f;
                float p1 = (sc[mf][1][r] > -1e29f) ? __expf(sc[mf][1][r] - mnew) : 0.f;
                pv[mf][0][r] = p0; pv[mf][1][r] = p1;
                psum[mf][r] = p0 + p1;
            }
        #pragma unroll
        for (int off = 1; off < 16; off <<= 1)
            #pragma unroll
            for (int mf = 0; mf < 2; ++mf)
                #pragma unroll
                for (int r = 0; r < 4; ++r)
                    psum[mf][r] += __shfl_xor(psum[mf][r], off);
        #pragma unroll
        for (int mf = 0; mf < 2; ++mf)
            #pragma unroll
            for (int r = 0; r < 4; ++r) lrow[mf][r] += psum[mf][r];

        #pragma unroll
        for (int mf = 0; mf < 2; ++mf)
            #pragma unroll
            for (int r = 0; r < 4; ++r) {
                int row = kq * 4 + r;
                int c0 = r16 ^ ((row & 7) << 3);
                int c1 = (16 + r16) ^ ((row & 7) << 3);
                *(unsigned short*)(pl + mf * 2048 + row * 128 + c0 * 2) = f2bf(pv[mf][0][r]);
                *(unsigned short*)(pl + mf * 2048 + row * 128 + c1 * 2) = f2bf(pv[mf][1][r]);
            }
        short8 pa[2];
        #pragma unroll
        for (int mf = 0; mf < 2; ++mf)
            pa[mf] = *(const short8*)(pl + mf * 2048 + r16 * 128 + ((kq ^ (r16 & 7)) * 16));
        #pragma unroll
        for (int nn = 0; nn < 4; ++nn) {
            short8 vf = *(const short8*)(vp + (size_t)(nn * 16 + r16) * SEQ + k0 + kq * 8);
            po[0][nn] = __builtin_amdgcn_mfma_f32_16x16x32_bf16(pa[0], vf, po[0][nn], 0, 0, 0);
            po[1][nn] = __builtin_amdgcn_mfma_f32_16x16x32_bf16(pa[1], vf, po[1][nn], 0, 0, 0);
        }
    }

    const int b = bh >> 4, h = bh & 15;
    #pragma unroll
    for (int mf = 0; mf < 2; ++mf)
        #pragma unroll
        for (int nn = 0; nn < 4; ++nn)
            #pragma unroll
            for (int r = 0; r < 4; ++r) {
                int s = q0 + mf * 16 + kq * 4 + r;
                float val = po[mf][nn][r] / lrow[mf][r];
                y[((size_t)(b * SEQ + s)) * E_DIM + h * HDIM + nn * 16 + r16] = f2bf(val);
            }
}

extern "C" void kernel_launch(void* const* d_in, const int* in_sizes, int n_in,
                              void* d_out, int out_size, void* d_ws, size_t ws_size,
                              hipStream_t stream) {
    const float* x  = (const float*)d_in[0];
    const float* Wq = (const float*)d_in[1];
    const float* Wk = (const float*)d_in[2];
    const float* Wv = (const float*)d_in[3];
    const float* Wo = (const float*)d_in[4];
    const float* bq = (const float*)d_in[5];
    const float* bk = (const float*)d_in[6];
    const float* bv = (const float*)d_in[7];
    const float* bo = (const float*)d_in[8];
    float* out = (float*)d_out;

    char* ws = (char*)d_ws;
    unsigned short* xb  = (unsigned short*)(ws);                        // 8 MB
    unsigned short* wqb = (unsigned short*)(ws + ((size_t)8 << 20));    // 2 MB
    unsigned short* wkb = (unsigned short*)(ws + ((size_t)10 << 20));   // 2 MB
    unsigned short* wvb = (unsigned short*)(ws + ((size_t)12 << 20));   // 2 MB
    unsigned short* wob = (unsigned short*)(ws + ((size_t)14 << 20));   // 2 MB
    unsigned short* qw  = (unsigned short*)(ws + ((size_t)16 << 20));   // 8 MB
    unsigned short* kw  = (unsigned short*)(ws + ((size_t)24 << 20));   // 8 MB
    unsigned short* vTw = (unsigned short*)(ws + ((size_t)40 << 20));   // 8 MB
    unsigned short* yw  = (unsigned short*)(ws + ((size_t)48 << 20));   // 8 MB

    conv_all<<<dim3(1024, 8), 256, 0, stream>>>(x, Wq, Wk, Wv, Wo, xb, wqb, wkb, wvb, wob);

    gemm8_qkv<<<dim3(16, 12), 512, 0, stream>>>(xb, wqb, wkb, wvb, bq, bk, bv, qw, kw, vTw);
    attn_swa<<<512, 256, 0, stream>>>(qw, kw, vTw, yw);
    gemm_out<<<dim3(32, 8), 256, 0, stream>>>(yw, wob, bo, out);
}

// Round 5
// 162.197 us; speedup vs baseline: 1.2439x; 1.0239x over previous
//
#include <hip/hip_runtime.h>

#define E_DIM 1024
#define NHEAD 16
#define HDIM 64
#define SEQ 2048
#define NBATCH 2
#define WIN 256
#define MTOK (NBATCH * SEQ) // 4096
#define BKT 32              // K per pipeline tile
#define NT (E_DIM / BKT)    // 32 tiles

typedef __attribute__((ext_vector_type(4))) float f32x4;
typedef __attribute__((ext_vector_type(8))) short short8;
typedef __attribute__((ext_vector_type(4))) unsigned short u16x4;

#define AS1 __attribute__((address_space(1)))
#define AS3 __attribute__((address_space(3)))

__device__ __forceinline__ void gll16(const void* g, void* l) {
    __builtin_amdgcn_global_load_lds((const AS1 void*)g, (AS3 void*)l, 16, 0, 0);
}

__device__ __forceinline__ unsigned short f2bf(float f) {
    union { float f; unsigned u; } a; a.f = f;
    unsigned r = a.u + 0x7fffu + ((a.u >> 16) & 1u);
    return (unsigned short)(r >> 16);
}

// ---------------- fused fp32 -> bf16 conversion: x (4 segs) + 4 weights ----------------
__global__ __launch_bounds__(256) void conv_all(const float* __restrict__ x,
        const float* __restrict__ w0, const float* __restrict__ w1,
        const float* __restrict__ w2, const float* __restrict__ w3,
        unsigned short* __restrict__ xo,
        unsigned short* __restrict__ o0, unsigned short* __restrict__ o1,
        unsigned short* __restrict__ o2, unsigned short* __restrict__ o3) {
    const int seg = blockIdx.y;   // 0..3: x quarters; 4..7: weights
    const float* src;
    unsigned short* dst;
    if (seg < 4) { src = x + (size_t)seg * 1048576; dst = xo + (size_t)seg * 1048576; }
    else {
        src = (seg == 4) ? w0 : (seg == 5) ? w1 : (seg == 6) ? w2 : w3;
        dst = (seg == 4) ? o0 : (seg == 5) ? o1 : (seg == 6) ? o2 : o3;
    }
    int i = blockIdx.x * 256 + threadIdx.x;
    float4 v = ((const float4*)src)[i];
    u16x4 o;
    o[0] = f2bf(v.x); o[1] = f2bf(v.y); o[2] = f2bf(v.z); o[3] = f2bf(v.w);
    ((u16x4*)dst)[i] = o;
}

// ---------------- QKV GEMM: single-barrier-per-tile, 4-deep LDS pipeline ----------------
__global__ __launch_bounds__(512, 2) void gemm8_qkv(const unsigned short* __restrict__ xb,
        const unsigned short* __restrict__ wqb, const unsigned short* __restrict__ wkb,
        const unsigned short* __restrict__ wvb,
        const float* __restrict__ bq, const float* __restrict__ bk, const float* __restrict__ bv,
        unsigned short* __restrict__ qo, unsigned short* __restrict__ ko,
        unsigned short* __restrict__ vTo) {
    __shared__ char lds[131072];
    const int tid = threadIdx.x;
    const int w = tid >> 6, l = tid & 63;
    const int r16 = l & 15, kq = l >> 4;
    const int wm = w >> 2, wn = w & 3;
    const int m0 = blockIdx.x * 256;
    const int by = blockIdx.y;            // 0..11
    const int mat = by >> 2;              // 0:Q 1:K 2:V
    const int nb = (by & 3) * 256;
    const unsigned short* Bw = (mat == 0) ? wqb : (mat == 1) ? wkb : wvb;

    const int srow = tid >> 2;
    const int sslot = tid & 3;
    const int fsw = (srow >> 1) & 3;
    const int gslot = (sslot ^ fsw) * 8;
    const unsigned short* aSrc0 = xb + (size_t)(m0 + srow) * E_DIM + gslot;
    const unsigned short* aSrc1 = aSrc0 + (size_t)128 * E_DIM;
    const unsigned short* bSrc0 = Bw + (size_t)(nb + srow) * E_DIM + gslot;
    const unsigned short* bSrc1 = bSrc0 + (size_t)128 * E_DIM;
    const int dstOff = w * 1024;

#define STAGE_A(t) { char* d_ = lds + ((t) & 3) * 32768 + dstOff; \
                     gll16(aSrc0 + (t) * BKT, d_); gll16(aSrc1 + (t) * BKT, d_ + 8192); }
#define STAGE_B(t) { char* d_ = lds + ((t) & 3) * 32768 + 16384 + dstOff; \
                     gll16(bSrc0 + (t) * BKT, d_); gll16(bSrc1 + (t) * BKT, d_ + 8192); }

    f32x4 acc[8][4];
    #pragma unroll
    for (int m = 0; m < 8; ++m)
        #pragma unroll
        for (int n = 0; n < 4; ++n)
            acc[m][n] = (f32x4){0.f, 0.f, 0.f, 0.f};

    STAGE_A(0); STAGE_B(0); STAGE_A(1); STAGE_B(1);

    const int fs = (r16 >> 1) & 3;
    const int rdoff = (kq ^ fs) * 16;

    for (int t = 0; t < NT; ++t) {
        if (t < NT - 1) { asm volatile("s_waitcnt vmcnt(4)" ::: "memory"); }
        else            { asm volatile("s_waitcnt vmcnt(0)" ::: "memory"); }
        __builtin_amdgcn_sched_barrier(0);
        __builtin_amdgcn_s_barrier();
        __builtin_amdgcn_sched_barrier(0);
        char* la = lds + (t & 3) * 32768;
        char* lb = la + 16384;
        short8 bfr[4], af[8];
        #pragma unroll
        for (int n = 0; n < 4; ++n)
            bfr[n] = *(const short8*)(lb + (wn * 64 + n * 16 + r16) * 64 + rdoff);
        #pragma unroll
        for (int j = 0; j < 8; ++j)
            af[j] = *(const short8*)(la + (wm * 128 + j * 16 + r16) * 64 + rdoff);
        if (t + 2 < NT) { STAGE_A(t + 2); STAGE_B(t + 2); }
        __builtin_amdgcn_s_setprio(1);
        #pragma unroll
        for (int j = 0; j < 8; ++j)
            #pragma unroll
            for (int n = 0; n < 4; ++n)
                acc[j][n] = __builtin_amdgcn_mfma_f32_16x16x32_bf16(af[j], bfr[n], acc[j][n], 0, 0, 0);
        __builtin_amdgcn_s_setprio(0);
    }
#undef STAGE_A
#undef STAGE_B

    const float* bias = (mat == 0) ? bq : (mat == 1) ? bk : bv;
    const float scale = (mat == 0) ? 0.125f : 1.0f;   // D^-0.5 folded into Q
    #pragma unroll
    for (int n = 0; n < 4; ++n) {
        int e = nb + wn * 64 + n * 16 + r16;
        float bb = bias[e];
        int h = e >> 6, d = e & 63;
        #pragma unroll
        for (int m = 0; m < 8; ++m) {
            int tok = m0 + wm * 128 + m * 16 + kq * 4;
            int b = tok >> 11, s = tok & (SEQ - 1);
            if (mat == 2) {
                u16x4 o;
                #pragma unroll
                for (int r = 0; r < 4; ++r) o[r] = f2bf(acc[m][n][r] + bb);
                *(u16x4*)(vTo + ((size_t)(b * NHEAD + h) * HDIM + d) * SEQ + s) = o;
            } else {
                unsigned short* dst = (mat == 0) ? qo : ko;
                #pragma unroll
                for (int r = 0; r < 4; ++r) {
                    float val = (acc[m][n][r] + bb) * scale;
                    dst[((size_t)(b * NHEAD + h) * SEQ + s + r) * HDIM + d] = f2bf(val);
                }
            }
        }
    }
}

// ---------------- output projection: same structure at 128x128, 4 waves ----------------
__global__ __launch_bounds__(256, 2) void gemm_out(const unsigned short* __restrict__ yb,
        const unsigned short* __restrict__ wob, const float* __restrict__ bo,
        float* __restrict__ out) {
    __shared__ char lds[65536];
    const int tid = threadIdx.x;
    const int w = tid >> 6, l = tid & 63;
    const int r16 = l & 15, kq = l >> 4;
    const int wr = w >> 1, wc = w & 1;
    const int m0 = blockIdx.x * 128;
    const int n0 = blockIdx.y * 128;

    const int srow = tid >> 2;
    const int sslot = tid & 3;
    const int fsw = (srow >> 1) & 3;
    const int gslot = (sslot ^ fsw) * 8;
    const unsigned short* aSrc0 = yb + (size_t)(m0 + srow) * E_DIM + gslot;
    const unsigned short* aSrc1 = aSrc0 + (size_t)64 * E_DIM;
    const unsigned short* bSrc0 = wob + (size_t)(n0 + srow) * E_DIM + gslot;
    const unsigned short* bSrc1 = bSrc0 + (size_t)64 * E_DIM;
    const int dstOff = w * 1024;

#define STAGE_A(t) { char* d_ = lds + ((t) & 3) * 16384 + dstOff; \
                     gll16(aSrc0 + (t) * BKT, d_); gll16(aSrc1 + (t) * BKT, d_ + 4096); }
#define STAGE_B(t) { char* d_ = lds + ((t) & 3) * 16384 + 8192 + dstOff; \
                     gll16(bSrc0 + (t) * BKT, d_); gll16(bSrc1 + (t) * BKT, d_ + 4096); }

    f32x4 acc[4][4];
    #pragma unroll
    for (int m = 0; m < 4; ++m)
        #pragma unroll
        for (int n = 0; n < 4; ++n)
            acc[m][n] = (f32x4){0.f, 0.f, 0.f, 0.f};

    STAGE_A(0); STAGE_B(0); STAGE_A(1); STAGE_B(1);

    const int fs = (r16 >> 1) & 3;
    const int rdoff = (kq ^ fs) * 16;

    for (int t = 0; t < NT; ++t) {
        if (t < NT - 1) { asm volatile("s_waitcnt vmcnt(4)" ::: "memory"); }
        else            { asm volatile("s_waitcnt vmcnt(0)" ::: "memory"); }
        __builtin_amdgcn_sched_barrier(0);
        __builtin_amdgcn_s_barrier();
        __builtin_amdgcn_sched_barrier(0);
        char* la = lds + (t & 3) * 16384;
        char* lb = la + 8192;
        short8 bfr[4], af[4];
        #pragma unroll
        for (int n = 0; n < 4; ++n)
            bfr[n] = *(const short8*)(lb + (wc * 64 + n * 16 + r16) * 64 + rdoff);
        #pragma unroll
        for (int m = 0; m < 4; ++m)
            af[m] = *(const short8*)(la + (wr * 64 + m * 16 + r16) * 64 + rdoff);
        if (t + 2 < NT) { STAGE_A(t + 2); STAGE_B(t + 2); }
        __builtin_amdgcn_s_setprio(1);
        #pragma unroll
        for (int m = 0; m < 4; ++m)
            #pragma unroll
            for (int n = 0; n < 4; ++n)
                acc[m][n] = __builtin_amdgcn_mfma_f32_16x16x32_bf16(af[m], bfr[n], acc[m][n], 0, 0, 0);
        __builtin_amdgcn_s_setprio(0);
    }
#undef STAGE_A
#undef STAGE_B

    #pragma unroll
    for (int n = 0; n < 4; ++n) {
        int e = n0 + wc * 64 + n * 16 + r16;
        float bb = bo[e];
        #pragma unroll
        for (int m = 0; m < 4; ++m) {
            #pragma unroll
            for (int r = 0; r < 4; ++r) {
                int tok = m0 + wr * 64 + m * 16 + kq * 4 + r;
                out[(size_t)tok * E_DIM + e] = acc[m][n][r] + bb;
            }
        }
    }
}

// ---------------- sliding-window flash attention: 32 q-rows per wave ----------------
// MODE: 0 = interior (no mask), 1 = head tile (key < qrow-WIN masked), 2 = tail (key > qrow masked)
template<int MODE, bool PRE>
__device__ __forceinline__ void attn_tile(int k0,
        const unsigned short* __restrict__ kp, const unsigned short* __restrict__ vp,
        int r16, int kq, char* pl,
        const short8 (&qf)[2][2], short8 (&kf)[2][2],
        f32x4 (&po)[2][4], float (&mrow)[2][4], float (&lsum)[2][4]) {
    // QK^T for current tile
    f32x4 sc[2][2];
    #pragma unroll
    for (int mf = 0; mf < 2; ++mf)
        #pragma unroll
        for (int n = 0; n < 2; ++n) {
            f32x4 z = {0.f, 0.f, 0.f, 0.f};
            z = __builtin_amdgcn_mfma_f32_16x16x32_bf16(qf[mf][0], kf[n][0], z, 0, 0, 0);
            sc[mf][n] = __builtin_amdgcn_mfma_f32_16x16x32_bf16(qf[mf][1], kf[n][1], z, 0, 0, 0);
        }
    // prefetch next tile's K (latency hidden under softmax VALU below)
    if (PRE) {
        #pragma unroll
        for (int n = 0; n < 2; ++n) {
            const unsigned short* kr = kp + (size_t)(k0 + 32 + n * 16 + r16) * HDIM + kq * 8;
            kf[n][0] = *(const short8*)(kr);
            kf[n][1] = *(const short8*)(kr + 32);
        }
    }
    // V for current tile (latency hidden under softmax VALU)
    short8 vf[4];
    #pragma unroll
    for (int nn = 0; nn < 4; ++nn)
        vf[nn] = *(const short8*)(vp + (size_t)(nn * 16 + r16) * SEQ + k0 + kq * 8);

    // masking (boundary tiles only) + row max
    float tmax[2][4];
    #pragma unroll
    for (int mf = 0; mf < 2; ++mf)
        #pragma unroll
        for (int r = 0; r < 4; ++r) {
            int rel = mf * 16 + kq * 4 + r;       // row index within the 32-row q-block
            if (MODE == 1) {
                if (r16 < rel)      sc[mf][0][r] = -1e30f;
                if (16 + r16 < rel) sc[mf][1][r] = -1e30f;
            }
            if (MODE == 2) {
                if (r16 > rel)      sc[mf][0][r] = -1e30f;
                if (16 + r16 > rel) sc[mf][1][r] = -1e30f;
            }
            tmax[mf][r] = fmaxf(sc[mf][0][r], sc[mf][1][r]);
        }
    #pragma unroll
    for (int off = 1; off < 16; off <<= 1)
        #pragma unroll
        for (int mf = 0; mf < 2; ++mf)
            #pragma unroll
            for (int r = 0; r < 4; ++r)
                tmax[mf][r] = fmaxf(tmax[mf][r], __shfl_xor(tmax[mf][r], off));
    // online softmax; lsum stays a PER-LANE partial (reduced once after the loop)
    float pv[2][2][4];
    #pragma unroll
    for (int mf = 0; mf < 2; ++mf)
        #pragma unroll
        for (int r = 0; r < 4; ++r) {
            float mnew = fmaxf(mrow[mf][r], tmax[mf][r]);
            float resc = __expf(mrow[mf][r] - mnew);
            mrow[mf][r] = mnew;
            float p0 = __expf(sc[mf][0][r] - mnew);   // masked scores -> exp(-1e30) = 0
            float p1 = __expf(sc[mf][1][r] - mnew);
            lsum[mf][r] = lsum[mf][r] * resc + p0 + p1;
            po[mf][0][r] *= resc; po[mf][1][r] *= resc;
            po[mf][2][r] *= resc; po[mf][3][r] *= resc;
            pv[mf][0][r] = p0; pv[mf][1][r] = p1;
        }
    // P (C-frag) -> per-wave swizzled LDS -> A-frag
    #pragma unroll
    for (int mf = 0; mf < 2; ++mf)
        #pragma unroll
        for (int r = 0; r < 4; ++r) {
            int row = kq * 4 + r;
            int c0 = r16 ^ ((row & 7) << 3);
            int c1 = c0 ^ 16;
            *(unsigned short*)(pl + mf * 2048 + row * 128 + c0 * 2) = f2bf(pv[mf][0][r]);
            *(unsigned short*)(pl + mf * 2048 + row * 128 + c1 * 2) = f2bf(pv[mf][1][r]);
        }
    short8 pa[2];
    #pragma unroll
    for (int mf = 0; mf < 2; ++mf)
        pa[mf] = *(const short8*)(pl + mf * 2048 + r16 * 128 + ((kq ^ (r16 & 7)) * 16));
    #pragma unroll
    for (int nn = 0; nn < 4; ++nn) {
        po[0][nn] = __builtin_amdgcn_mfma_f32_16x16x32_bf16(pa[0], vf[nn], po[0][nn], 0, 0, 0);
        po[1][nn] = __builtin_amdgcn_mfma_f32_16x16x32_bf16(pa[1], vf[nn], po[1][nn], 0, 0, 0);
    }
}

__global__ __launch_bounds__(256) void attn_swa(const unsigned short* __restrict__ q,
                                                const unsigned short* __restrict__ k,
                                                const unsigned short* __restrict__ vT,
                                                unsigned short* __restrict__ y) {
    __shared__ char plds[4 * 4096];
    const int t = threadIdx.x;
    const int w = t >> 6, l = t & 63;
    const int r16 = l & 15, kq = l >> 4;
    const int wid = blockIdx.x * 4 + w;
    const int bh = wid >> 6;
    const int q0 = (wid & 63) * 32;
    const unsigned short* qp = q + (size_t)bh * SEQ * HDIM;
    const unsigned short* kp = k + (size_t)bh * SEQ * HDIM;
    const unsigned short* vp = vT + (size_t)bh * HDIM * SEQ;
    char* pl = plds + w * 4096;

    short8 qf[2][2];
    #pragma unroll
    for (int mf = 0; mf < 2; ++mf) {
        const unsigned short* qr = qp + (q0 + mf * 16 + r16) * HDIM + kq * 8;
        qf[mf][0] = *(const short8*)(qr);
        qf[mf][1] = *(const short8*)(qr + 32);
    }

    f32x4 po[2][4];
    float mrow[2][4], lsum[2][4];
    #pragma unroll
    for (int mf = 0; mf < 2; ++mf) {
        #pragma unroll
        for (int nn = 0; nn < 4; ++nn) po[mf][nn] = (f32x4){0.f, 0.f, 0.f, 0.f};
        #pragma unroll
        for (int r = 0; r < 4; ++r) { mrow[mf][r] = -1e30f; lsum[mf][r] = 0.f; }
    }

    const int kstart = (q0 >= WIN) ? (q0 - WIN) : 0;
    short8 kf[2][2];
    #pragma unroll
    for (int n = 0; n < 2; ++n) {
        const unsigned short* kr = kp + (size_t)(kstart + n * 16 + r16) * HDIM + kq * 8;
        kf[n][0] = *(const short8*)(kr);
        kf[n][1] = *(const short8*)(kr + 32);
    }

    int k0 = kstart;
    if (q0 >= WIN) {   // head tile: lower-edge mask
        attn_tile<1, true>(k0, kp, vp, r16, kq, pl, qf, kf, po, mrow, lsum);
        k0 += 32;
    }
    for (; k0 < q0; k0 += 32)   // interior tiles: no mask
        attn_tile<0, true>(k0, kp, vp, r16, kq, pl, qf, kf, po, mrow, lsum);
    // tail tile: causal mask, no prefetch
    attn_tile<2, false>(q0, kp, vp, r16, kq, pl, qf, kf, po, mrow, lsum);

    // final cross-lane reduction of the deferred per-lane l-sums
    #pragma unroll
    for (int off = 1; off < 16; off <<= 1)
        #pragma unroll
        for (int mf = 0; mf < 2; ++mf)
            #pragma unroll
            for (int r = 0; r < 4; ++r)
                lsum[mf][r] += __shfl_xor(lsum[mf][r], off);

    const int b = bh >> 4, h = bh & 15;
    #pragma unroll
    for (int mf = 0; mf < 2; ++mf)
        #pragma unroll
        for (int nn = 0; nn < 4; ++nn)
            #pragma unroll
            for (int r = 0; r < 4; ++r) {
                int s = q0 + mf * 16 + kq * 4 + r;
                float val = po[mf][nn][r] / lsum[mf][r];
                y[((size_t)(b * SEQ + s)) * E_DIM + h * HDIM + nn * 16 + r16] = f2bf(val);
            }
}

extern "C" void kernel_launch(void* const* d_in, const int* in_sizes, int n_in,
                              void* d_out, int out_size, void* d_ws, size_t ws_size,
                              hipStream_t stream) {
    const float* x  = (const float*)d_in[0];
    const float* Wq = (const float*)d_in[1];
    const float* Wk = (const float*)d_in[2];
    const float* Wv = (const float*)d_in[3];
    const float* Wo = (const float*)d_in[4];
    const float* bq = (const float*)d_in[5];
    const float* bk = (const float*)d_in[6];
    const float* bv = (const float*)d_in[7];
    const float* bo = (const float*)d_in[8];
    float* out = (float*)d_out;

    char* ws = (char*)d_ws;
    unsigned short* xb  = (unsigned short*)(ws);                        // 8 MB
    unsigned short* wqb = (unsigned short*)(ws + ((size_t)8 << 20));    // 2 MB
    unsigned short* wkb = (unsigned short*)(ws + ((size_t)10 << 20));   // 2 MB
    unsigned short* wvb = (unsigned short*)(ws + ((size_t)12 << 20));   // 2 MB
    unsigned short* wob = (unsigned short*)(ws + ((size_t)14 << 20));   // 2 MB
    unsigned short* qw  = (unsigned short*)(ws + ((size_t)16 << 20));   // 8 MB
    unsigned short* kw  = (unsigned short*)(ws + ((size_t)24 << 20));   // 8 MB
    unsigned short* vTw = (unsigned short*)(ws + ((size_t)40 << 20));   // 8 MB
    unsigned short* yw  = (unsigned short*)(ws + ((size_t)48 << 20));   // 8 MB

    conv_all<<<dim3(1024, 8), 256, 0, stream>>>(x, Wq, Wk, Wv, Wo, xb, wqb, wkb, wvb, wob);

    gemm8_qkv<<<dim3(16, 12), 512, 0, stream>>>(xb, wqb, wkb, wvb, bq, bk, bv, qw, kw, vTw);
    attn_swa<<<512, 256, 0, stream>>>(qw, kw, vTw, yw);
    gemm_out<<<dim3(32, 8), 256, 0, stream>>>(yw, wob, bo, out);
}